// Round 2
// baseline (4470.906 us; speedup 1.0000x reference)
//
#include <hip/hip_runtime.h>

#define NN 100000
#define EE 1600000
#define IND 5
#define HID 64
#define EDD 4
#define ODD 3
#define NL 3
#define BNEPS 1e-5f

#define EPB 128      // edges per block in edge kernel
#define PITCH 132    // LDS row pitch (floats), multiple of 4, breaks bank conflicts

__device__ __forceinline__ float frelu(float v) { return fmaxf(v, 0.f); }

// -------------------- h0 = relu(x @ Win + bin) --------------------
__global__ __launch_bounds__(256) void k_input(const float* __restrict__ x,
    const float* __restrict__ Win, const float* __restrict__ bin,
    float* __restrict__ h)
{
    __shared__ float sX[32 * IND];
    __shared__ float sW[IND * HID];
    __shared__ float sB[HID];
    const int t = threadIdx.x;
    const int n0 = blockIdx.x * 32;
    if (t < 32 * IND) sX[t] = x[(size_t)n0 * IND + t];
    for (int i = t; i < IND * HID; i += 256) sW[i] = Win[i];
    if (t < HID) sB[t] = bin[t];
    __syncthreads();
    const int nl = t >> 3;
    const int j0 = (t & 7) * 8;
    float acc[8];
#pragma unroll
    for (int j = 0; j < 8; ++j) acc[j] = sB[j0 + j];
#pragma unroll
    for (int k = 0; k < IND; ++k) {
        const float xv = sX[nl * IND + k];
#pragma unroll
        for (int j = 0; j < 8; ++j) acc[j] = fmaf(xv, sW[k * HID + j0 + j], acc[j]);
    }
    float* hp = h + (size_t)(n0 + nl) * HID + j0;
#pragma unroll
    for (int j = 0; j < 8; ++j) hp[j] = frelu(acc[j]);
}

// ---- per-layer edge kernel: gather h[src] -> MLP -> atomic scatter to agg ----
__global__ __launch_bounds__(256) void k_edge(const float* __restrict__ h,
    const int* __restrict__ ei32, const float* __restrict__ ea,
    const float* __restrict__ W1, const float* __restrict__ b1,
    const float* __restrict__ W2, const float* __restrict__ b2,
    float* __restrict__ agg)
{
    __shared__ float sAT[68 * PITCH];   // A^T tile; reused as T1^T (64 rows) for stage 2
    __shared__ float sW1[68 * HID];
    __shared__ float sW2[HID * HID];
    __shared__ float sB1[HID];
    __shared__ float sB2[HID];
    __shared__ int   sDst[EPB];
    const int t = threadIdx.x;
    const size_t e0 = (size_t)blockIdx.x * EPB;

    // int64-vs-int32 edge_index detection (uniform across grid; high words of
    // little-endian int64 are zero; int32 random values in [0,1e5) are not).
    const bool w64 = (ei32[1] == 0) && (ei32[3] == 0);
    const int sh = w64 ? 1 : 0;

    for (int i = t; i < 68 * HID; i += 256) sW1[i] = W1[i];
    for (int i = t; i < HID * HID; i += 256) sW2[i] = W2[i];
    if (t < HID) { sB1[t] = b1[t]; sB2[t] = b2[t]; }
    if (t < EPB) sDst[t] = ei32[(EE + e0 + t) << sh];

    {   // gather staging: 2 threads per edge, transposed into LDS
        const int e = t >> 1, half = t & 1;
        const int src = ei32[(e0 + e) << sh];
        const float* hp = h + (size_t)src * HID + half * 32;
#pragma unroll
        for (int k = 0; k < 32; k += 4) {
            const float4 v = *(const float4*)(hp + k);
            sAT[(half * 32 + k + 0) * PITCH + e] = v.x;
            sAT[(half * 32 + k + 1) * PITCH + e] = v.y;
            sAT[(half * 32 + k + 2) * PITCH + e] = v.z;
            sAT[(half * 32 + k + 3) * PITCH + e] = v.w;
        }
        if (half) {
            const float4 a = *(const float4*)(ea + (e0 + e) * EDD);
            sAT[(64 + 0) * PITCH + e] = a.x;
            sAT[(64 + 1) * PITCH + e] = a.y;
            sAT[(64 + 2) * PITCH + e] = a.z;
            sAT[(64 + 3) * PITCH + e] = a.w;
        }
    }
    __syncthreads();

    const int og = t & 15, eg = t >> 4;
    const int j0 = og * 4, le0 = eg * 8;
    float acc[8][4];
#pragma unroll
    for (int i = 0; i < 8; ++i)
#pragma unroll
        for (int j = 0; j < 4; ++j) acc[i][j] = sB1[j0 + j];

    for (int k = 0; k < 68; ++k) {   // stage 1: [128 x 68] @ [68 x 64]
        const float4 b  = *(const float4*)&sW1[k * HID + j0];
        const float4 a0 = *(const float4*)&sAT[k * PITCH + le0];
        const float4 a1 = *(const float4*)&sAT[k * PITCH + le0 + 4];
        const float av[8] = {a0.x, a0.y, a0.z, a0.w, a1.x, a1.y, a1.z, a1.w};
        const float bv[4] = {b.x, b.y, b.z, b.w};
#pragma unroll
        for (int i = 0; i < 8; ++i)
#pragma unroll
            for (int j = 0; j < 4; ++j) acc[i][j] = fmaf(av[i], bv[j], acc[i][j]);
    }
    __syncthreads();

    // write relu(t1) transposed into sAT (rows 0..63)
#pragma unroll
    for (int j = 0; j < 4; ++j) {
        const float4 w0 = make_float4(frelu(acc[0][j]), frelu(acc[1][j]),
                                      frelu(acc[2][j]), frelu(acc[3][j]));
        const float4 w1 = make_float4(frelu(acc[4][j]), frelu(acc[5][j]),
                                      frelu(acc[6][j]), frelu(acc[7][j]));
        *(float4*)&sAT[(j0 + j) * PITCH + le0] = w0;
        *(float4*)&sAT[(j0 + j) * PITCH + le0 + 4] = w1;
    }
    __syncthreads();

#pragma unroll
    for (int i = 0; i < 8; ++i)
#pragma unroll
        for (int j = 0; j < 4; ++j) acc[i][j] = sB2[j0 + j];

    for (int k = 0; k < HID; ++k) {  // stage 2: [128 x 64] @ [64 x 64]
        const float4 b  = *(const float4*)&sW2[k * HID + j0];
        const float4 a0 = *(const float4*)&sAT[k * PITCH + le0];
        const float4 a1 = *(const float4*)&sAT[k * PITCH + le0 + 4];
        const float av[8] = {a0.x, a0.y, a0.z, a0.w, a1.x, a1.y, a1.z, a1.w};
        const float bv[4] = {b.x, b.y, b.z, b.w};
#pragma unroll
        for (int i = 0; i < 8; ++i)
#pragma unroll
            for (int j = 0; j < 4; ++j) acc[i][j] = fmaf(av[i], bv[j], acc[i][j]);
    }

    // scatter-add (no relu after stage 2)
#pragma unroll
    for (int i = 0; i < 8; ++i) {
        const int dst = sDst[le0 + i];
        float* ap = agg + (size_t)dst * HID + j0;
#pragma unroll
        for (int j = 0; j < 4; ++j) atomicAdd(ap + j, acc[i][j]);
    }
}

// -------------------- BN stats: per-channel sum & sumsq over nodes --------------------
__global__ __launch_bounds__(256) void k_bnstats(const float* __restrict__ agg,
    float* __restrict__ stats)
{
    const int c = threadIdx.x & 63;
    const int rg = threadIdx.x >> 6;
    float s = 0.f, ss = 0.f;
    for (size_t n = (size_t)blockIdx.x * 4 + rg; n < NN; n += (size_t)gridDim.x * 4) {
        const float v = agg[n * HID + c];
        s += v;
        ss = fmaf(v, v, ss);
    }
    __shared__ float rs[4][64];
    __shared__ float rss[4][64];
    rs[rg][c] = s; rss[rg][c] = ss;
    __syncthreads();
    if (rg == 0) {
        s  = rs[0][c] + rs[1][c] + rs[2][c] + rs[3][c];
        ss = rss[0][c] + rss[1][c] + rss[2][c] + rss[3][c];
        atomicAdd(&stats[c], s);
        atomicAdd(&stats[64 + c], ss);
    }
}

// -------------------- h += relu(BN(agg)) --------------------
__global__ __launch_bounds__(256) void k_update(const float* __restrict__ agg,
    const float* __restrict__ stats, const float* __restrict__ gamma,
    const float* __restrict__ beta, float* __restrict__ h)
{
    const size_t i = (size_t)blockIdx.x * 256 + threadIdx.x;
    const int c = (int)(i & 63);
    const float mu  = stats[c] * (1.f / NN);
    const float var = fmaf(-mu, mu, stats[64 + c] * (1.f / NN));
    const float inv = rsqrtf(var + BNEPS);
    const float v = fmaf((agg[i] - mu) * inv, gamma[c], beta[c]);
    h[i] += frelu(v);
}

// -------------------- out = relu(h @ W3 + b3) @ W4 + b4 --------------------
__global__ __launch_bounds__(256) void k_out(const float* __restrict__ h,
    const float* __restrict__ W3, const float* __restrict__ b3,
    const float* __restrict__ W4, const float* __restrict__ b4,
    float* __restrict__ out)
{
    __shared__ float sAT[64 * PITCH];   // h^T tile; reused as o1^T
    __shared__ float sW3[HID * HID];
    __shared__ float sW4[HID * 4];
    __shared__ float sB3[HID];
    __shared__ float sB4[4];
    const int t = threadIdx.x;
    const size_t n0 = (size_t)blockIdx.x * 128;

    for (int i = t; i < HID * HID; i += 256) sW3[i] = W3[i];
    if (t < HID * ODD) sW4[(t / ODD) * 4 + (t % ODD)] = W4[t];
    if (t < HID) sB3[t] = b3[t];
    if (t < ODD) sB4[t] = b4[t];

    {
        const int e = t >> 1, half = t & 1;
        const size_t n = n0 + e;
        if (n < NN) {
            const float* hp = h + n * HID + half * 32;
#pragma unroll
            for (int k = 0; k < 32; k += 4) {
                const float4 v = *(const float4*)(hp + k);
                sAT[(half * 32 + k + 0) * PITCH + e] = v.x;
                sAT[(half * 32 + k + 1) * PITCH + e] = v.y;
                sAT[(half * 32 + k + 2) * PITCH + e] = v.z;
                sAT[(half * 32 + k + 3) * PITCH + e] = v.w;
            }
        } else {
#pragma unroll
            for (int k = 0; k < 32; ++k) sAT[(half * 32 + k) * PITCH + e] = 0.f;
        }
    }
    __syncthreads();

    const int og = t & 15, eg = t >> 4;
    const int j0 = og * 4, le0 = eg * 8;
    float acc[8][4];
#pragma unroll
    for (int i = 0; i < 8; ++i)
#pragma unroll
        for (int j = 0; j < 4; ++j) acc[i][j] = sB3[j0 + j];

    for (int k = 0; k < HID; ++k) {
        const float4 b  = *(const float4*)&sW3[k * HID + j0];
        const float4 a0 = *(const float4*)&sAT[k * PITCH + le0];
        const float4 a1 = *(const float4*)&sAT[k * PITCH + le0 + 4];
        const float av[8] = {a0.x, a0.y, a0.z, a0.w, a1.x, a1.y, a1.z, a1.w};
        const float bv[4] = {b.x, b.y, b.z, b.w};
#pragma unroll
        for (int i = 0; i < 8; ++i)
#pragma unroll
            for (int j = 0; j < 4; ++j) acc[i][j] = fmaf(av[i], bv[j], acc[i][j]);
    }
    __syncthreads();

#pragma unroll
    for (int j = 0; j < 4; ++j) {
        const float4 w0 = make_float4(frelu(acc[0][j]), frelu(acc[1][j]),
                                      frelu(acc[2][j]), frelu(acc[3][j]));
        const float4 w1 = make_float4(frelu(acc[4][j]), frelu(acc[5][j]),
                                      frelu(acc[6][j]), frelu(acc[7][j]));
        *(float4*)&sAT[(j0 + j) * PITCH + le0] = w0;
        *(float4*)&sAT[(j0 + j) * PITCH + le0 + 4] = w1;
    }
    __syncthreads();

    if (t < 128) {
        const size_t n = n0 + t;
        if (n < NN) {
            float o[3] = {sB4[0], sB4[1], sB4[2]};
            for (int k = 0; k < HID; ++k) {
                const float v = sAT[k * PITCH + t];
                o[0] = fmaf(v, sW4[k * 4 + 0], o[0]);
                o[1] = fmaf(v, sW4[k * 4 + 1], o[1]);
                o[2] = fmaf(v, sW4[k * 4 + 2], o[2]);
            }
            out[n * 3 + 0] = o[0];
            out[n * 3 + 1] = o[1];
            out[n * 3 + 2] = o[2];
        }
    }
}

extern "C" void kernel_launch(void* const* d_in, const int* in_sizes, int n_in,
                              void* d_out, int out_size, void* d_ws, size_t ws_size,
                              hipStream_t stream)
{
    const float* x   = (const float*)d_in[0];
    const int*   ei  = (const int*)d_in[1];
    const float* ea  = (const float*)d_in[2];
    const float* Win = (const float*)d_in[3];
    const float* bin = (const float*)d_in[4];
    const float* W1  = (const float*)d_in[5];
    const float* b1  = (const float*)d_in[6];
    const float* W2  = (const float*)d_in[7];
    const float* b2  = (const float*)d_in[8];
    const float* gam = (const float*)d_in[9];
    const float* bet = (const float*)d_in[10];
    const float* W3  = (const float*)d_in[11];
    const float* b3  = (const float*)d_in[12];
    const float* W4  = (const float*)d_in[13];
    const float* b4  = (const float*)d_in[14];
    float* out = (float*)d_out;

    float* h     = (float*)d_ws;                 // NN*HID f32
    float* agg   = h + (size_t)NN * HID;         // NN*HID f32
    float* stats = agg + (size_t)NN * HID;       // 128 f32

    k_input<<<NN / 32, 256, 0, stream>>>(x, Win, bin, h);

    for (int l = 0; l < NL; ++l) {
        hipMemsetAsync(agg, 0, ((size_t)NN * HID + 128) * sizeof(float), stream);
        k_edge<<<EE / EPB, 256, 0, stream>>>(h, ei, ea,
            W1 + (size_t)l * (HID + EDD) * HID, b1 + (size_t)l * HID,
            W2 + (size_t)l * HID * HID, b2 + (size_t)l * HID, agg);
        k_bnstats<<<512, 256, 0, stream>>>(agg, stats);
        k_update<<<(NN * HID) / 256, 256, 0, stream>>>(agg, stats,
            gam + (size_t)l * HID, bet + (size_t)l * HID, h);
    }

    k_out<<<(NN + 127) / 128, 256, 0, stream>>>(h, W3, b3, W4, b4, out);
}

// Round 5
// 2161.618 us; speedup vs baseline: 2.0683x; 2.0683x over previous
//
#include <hip/hip_runtime.h>

#define NN 100000
#define EE 1600000
#define IND 5
#define HID 64
#define EDD 4
#define ODD 3
#define NL 3
#define BNEPS 1e-5f

#define EPB 128      // edges per block in MLP kernel
#define PITCH 132    // LDS row pitch (floats)
#define NB 391       // ceil(NN/256) for the scan

__device__ __forceinline__ float frelu(float v) { return fmaxf(v, 0.f); }

__device__ __forceinline__ int ei_shift(const int* ei32) {
    // int64-vs-int32 edge_index detection (uniform): high words of LE int64 are 0.
    return ((ei32[1] == 0) && (ei32[3] == 0)) ? 1 : 0;
}

// -------------------- h0 = relu(x @ Win + bin) --------------------
__global__ __launch_bounds__(256) void k_input(const float* __restrict__ x,
    const float* __restrict__ Win, const float* __restrict__ bin,
    float* __restrict__ h)
{
    __shared__ float sX[32 * IND];
    __shared__ float sW[IND * HID];
    __shared__ float sB[HID];
    const int t = threadIdx.x;
    const int n0 = blockIdx.x * 32;
    if (t < 32 * IND) sX[t] = x[(size_t)n0 * IND + t];
    for (int i = t; i < IND * HID; i += 256) sW[i] = Win[i];
    if (t < HID) sB[t] = bin[t];
    __syncthreads();
    const int nl = t >> 3;
    const int j0 = (t & 7) * 8;
    float acc[8];
#pragma unroll
    for (int j = 0; j < 8; ++j) acc[j] = sB[j0 + j];
#pragma unroll
    for (int k = 0; k < IND; ++k) {
        const float xv = sX[nl * IND + k];
#pragma unroll
        for (int j = 0; j < 8; ++j) acc[j] = fmaf(xv, sW[k * HID + j0 + j], acc[j]);
    }
    float* hp = h + (size_t)(n0 + nl) * HID + j0;
#pragma unroll
    for (int j = 0; j < 8; ++j) hp[j] = frelu(acc[j]);
}

// -------------------- CSR build: histogram, scan, permute --------------------
__global__ __launch_bounds__(256) void k_hist(const int* __restrict__ ei32,
    int* __restrict__ deg)
{
    const int sh = ei_shift(ei32);
    const int e = blockIdx.x * 256 + threadIdx.x;
    if (e < EE) atomicAdd(&deg[ei32[(size_t)(EE + e) << sh]], 1);
}

__global__ __launch_bounds__(256) void k_part(const int* __restrict__ deg,
    int* __restrict__ bsum)
{
    const int t = threadIdx.x;
    const int i = blockIdx.x * 256 + t;
    int v = (i < NN) ? deg[i] : 0;
#pragma unroll
    for (int off = 32; off > 0; off >>= 1) v += __shfl_down(v, off, 64);
    __shared__ int wsum[4];
    if ((t & 63) == 0) wsum[t >> 6] = v;
    __syncthreads();
    if (t == 0) bsum[blockIdx.x] = wsum[0] + wsum[1] + wsum[2] + wsum[3];
}

__global__ void k_top(const int* __restrict__ bsum, int* __restrict__ bpre)
{
    if (threadIdx.x == 0) {
        int run = 0;
        for (int i = 0; i < NB; ++i) { bpre[i] = run; run += bsum[i]; }
    }
}

__global__ __launch_bounds__(256) void k_scan_add(const int* __restrict__ deg,
    const int* __restrict__ bpre, int* __restrict__ rowstart, int* __restrict__ cursor)
{
    __shared__ int sa[256], sb[256];
    const int t = threadIdx.x;
    const int i = blockIdx.x * 256 + t;
    const int v = (i < NN) ? deg[i] : 0;
    sa[t] = v;
    int* src = sa; int* dst = sb;
    for (int off = 1; off < 256; off <<= 1) {
        __syncthreads();
        dst[t] = (t >= off) ? (src[t] + src[t - off]) : src[t];
        int* tmp = src; src = dst; dst = tmp;
    }
    __syncthreads();
    const int excl = src[t] - v;
    if (i < NN) {
        const int rs = bpre[blockIdx.x] + excl;
        rowstart[i] = rs;
        cursor[i] = rs;
    }
    if (i == 0) rowstart[NN] = EE;
}

__global__ __launch_bounds__(256) void k_permute(const int* __restrict__ ei32,
    int* __restrict__ cursor, int* __restrict__ eperm)
{
    const int sh = ei_shift(ei32);
    const int e = blockIdx.x * 256 + threadIdx.x;
    if (e < EE) {
        const int d = ei32[(size_t)(EE + e) << sh];
        const int pos = atomicAdd(&cursor[d], 1);
        eperm[pos] = e;
    }
}

// ---- MLP over a chunk of dst-sorted edges; coalesced message writes ----
__global__ __launch_bounds__(256) void k_mlp(const float* __restrict__ h,
    const int* __restrict__ ei32, const float* __restrict__ ea,
    const int* __restrict__ eperm,
    const float* __restrict__ W1, const float* __restrict__ b1,
    const float* __restrict__ W2, const float* __restrict__ b2,
    float* __restrict__ m, int ebase)
{
    __shared__ float sAT[68 * PITCH];
    __shared__ float sW1[68 * HID];
    __shared__ float sW2[HID * HID];
    __shared__ float sB1[HID];
    __shared__ float sB2[HID];
    const int t = threadIdx.x;
    const int r0 = blockIdx.x * EPB;      // local row base within chunk
    const int sh = ei_shift(ei32);

    for (int i = t; i < 68 * HID; i += 256) sW1[i] = W1[i];
    for (int i = t; i < HID * HID; i += 256) sW2[i] = W2[i];
    if (t < HID) { sB1[t] = b1[t]; sB2[t] = b2[t]; }

    {   // gather staging: 2 threads per edge, transposed into LDS
        const int e = t >> 1, half = t & 1;
        const int eid = eperm[ebase + r0 + e];
        const int src = ei32[(size_t)eid << sh];
        const float* hp = h + (size_t)src * HID + half * 32;
#pragma unroll
        for (int k = 0; k < 32; k += 4) {
            const float4 v = *(const float4*)(hp + k);
            sAT[(half * 32 + k + 0) * PITCH + e] = v.x;
            sAT[(half * 32 + k + 1) * PITCH + e] = v.y;
            sAT[(half * 32 + k + 2) * PITCH + e] = v.z;
            sAT[(half * 32 + k + 3) * PITCH + e] = v.w;
        }
        if (half) {
            const float4 a = *(const float4*)(ea + (size_t)eid * EDD);
            sAT[(64 + 0) * PITCH + e] = a.x;
            sAT[(64 + 1) * PITCH + e] = a.y;
            sAT[(64 + 2) * PITCH + e] = a.z;
            sAT[(64 + 3) * PITCH + e] = a.w;
        }
    }
    __syncthreads();

    const int og = t & 15, eg = t >> 4;
    const int j0 = og * 4, le0 = eg * 8;
    float acc[8][4];
#pragma unroll
    for (int i = 0; i < 8; ++i)
#pragma unroll
        for (int j = 0; j < 4; ++j) acc[i][j] = sB1[j0 + j];

    for (int k = 0; k < 68; ++k) {   // stage 1: [128 x 68] @ [68 x 64]
        const float4 b  = *(const float4*)&sW1[k * HID + j0];
        const float4 a0 = *(const float4*)&sAT[k * PITCH + le0];
        const float4 a1 = *(const float4*)&sAT[k * PITCH + le0 + 4];
        const float av[8] = {a0.x, a0.y, a0.z, a0.w, a1.x, a1.y, a1.z, a1.w};
        const float bv[4] = {b.x, b.y, b.z, b.w};
#pragma unroll
        for (int i = 0; i < 8; ++i)
#pragma unroll
            for (int j = 0; j < 4; ++j) acc[i][j] = fmaf(av[i], bv[j], acc[i][j]);
    }
    __syncthreads();

#pragma unroll
    for (int j = 0; j < 4; ++j) {   // relu(t1) transposed back into sAT
        const float4 w0 = make_float4(frelu(acc[0][j]), frelu(acc[1][j]),
                                      frelu(acc[2][j]), frelu(acc[3][j]));
        const float4 w1 = make_float4(frelu(acc[4][j]), frelu(acc[5][j]),
                                      frelu(acc[6][j]), frelu(acc[7][j]));
        *(float4*)&sAT[(j0 + j) * PITCH + le0] = w0;
        *(float4*)&sAT[(j0 + j) * PITCH + le0 + 4] = w1;
    }
    __syncthreads();

#pragma unroll
    for (int i = 0; i < 8; ++i)
#pragma unroll
        for (int j = 0; j < 4; ++j) acc[i][j] = sB2[j0 + j];

    for (int k = 0; k < HID; ++k) {  // stage 2: [128 x 64] @ [64 x 64]
        const float4 b  = *(const float4*)&sW2[k * HID + j0];
        const float4 a0 = *(const float4*)&sAT[k * PITCH + le0];
        const float4 a1 = *(const float4*)&sAT[k * PITCH + le0 + 4];
        const float av[8] = {a0.x, a0.y, a0.z, a0.w, a1.x, a1.y, a1.z, a1.w};
        const float bv[4] = {b.x, b.y, b.z, b.w};
#pragma unroll
        for (int i = 0; i < 8; ++i)
#pragma unroll
            for (int j = 0; j < 4; ++j) acc[i][j] = fmaf(av[i], bv[j], acc[i][j]);
    }

    // coalesced message store (rows sorted by dst)
#pragma unroll
    for (int i = 0; i < 8; ++i) {
        float* mp = m + (size_t)(r0 + le0 + i) * HID + j0;
        *(float4*)mp = make_float4(acc[i][0], acc[i][1], acc[i][2], acc[i][3]);
    }
}

// ---- aggregate sorted messages per node (chunk [i0,i1) of sorted edge ids) ----
__global__ __launch_bounds__(256) void k_agg(const float* __restrict__ m,
    const int* __restrict__ rowstart, float* __restrict__ agg, int i0, int i1)
{
    const int g = threadIdx.x >> 6, c = threadIdx.x & 63;
    const int n = blockIdx.x * 4 + g;
    if (n >= NN) return;
    const int s = rowstart[n], e = rowstart[n + 1];
    const int lo = max(s, i0), hi = min(e, i1);
    if (lo >= hi) return;
    float sum = 0.f;
    for (int j = lo; j < hi; ++j) sum += m[(size_t)(j - i0) * HID + c];
    float* ap = agg + (size_t)n * HID + c;
    if (s >= i0 && e <= i1) *ap = sum;     // node fully inside this chunk
    else atomicAdd(ap, sum);               // boundary node (rare)
}

// ---- fallback path (atomic scatter), used only if ws_size is too small ----
__global__ __launch_bounds__(256) void k_edge(const float* __restrict__ h,
    const int* __restrict__ ei32, const float* __restrict__ ea,
    const float* __restrict__ W1, const float* __restrict__ b1,
    const float* __restrict__ W2, const float* __restrict__ b2,
    float* __restrict__ agg)
{
    __shared__ float sAT[68 * PITCH];
    __shared__ float sW1[68 * HID];
    __shared__ float sW2[HID * HID];
    __shared__ float sB1[HID];
    __shared__ float sB2[HID];
    __shared__ int   sDst[EPB];
    const int t = threadIdx.x;
    const size_t e0 = (size_t)blockIdx.x * EPB;
    const int sh = ei_shift(ei32);

    for (int i = t; i < 68 * HID; i += 256) sW1[i] = W1[i];
    for (int i = t; i < HID * HID; i += 256) sW2[i] = W2[i];
    if (t < HID) { sB1[t] = b1[t]; sB2[t] = b2[t]; }
    if (t < EPB) sDst[t] = ei32[(EE + e0 + t) << sh];

    {
        const int e = t >> 1, half = t & 1;
        const int src = ei32[(e0 + e) << sh];
        const float* hp = h + (size_t)src * HID + half * 32;
#pragma unroll
        for (int k = 0; k < 32; k += 4) {
            const float4 v = *(const float4*)(hp + k);
            sAT[(half * 32 + k + 0) * PITCH + e] = v.x;
            sAT[(half * 32 + k + 1) * PITCH + e] = v.y;
            sAT[(half * 32 + k + 2) * PITCH + e] = v.z;
            sAT[(half * 32 + k + 3) * PITCH + e] = v.w;
        }
        if (half) {
            const float4 a = *(const float4*)(ea + (e0 + e) * EDD);
            sAT[(64 + 0) * PITCH + e] = a.x;
            sAT[(64 + 1) * PITCH + e] = a.y;
            sAT[(64 + 2) * PITCH + e] = a.z;
            sAT[(64 + 3) * PITCH + e] = a.w;
        }
    }
    __syncthreads();

    const int og = t & 15, eg = t >> 4;
    const int j0 = og * 4, le0 = eg * 8;
    float acc[8][4];
#pragma unroll
    for (int i = 0; i < 8; ++i)
#pragma unroll
        for (int j = 0; j < 4; ++j) acc[i][j] = sB1[j0 + j];
    for (int k = 0; k < 68; ++k) {
        const float4 b  = *(const float4*)&sW1[k * HID + j0];
        const float4 a0 = *(const float4*)&sAT[k * PITCH + le0];
        const float4 a1 = *(const float4*)&sAT[k * PITCH + le0 + 4];
        const float av[8] = {a0.x, a0.y, a0.z, a0.w, a1.x, a1.y, a1.z, a1.w};
        const float bv[4] = {b.x, b.y, b.z, b.w};
#pragma unroll
        for (int i = 0; i < 8; ++i)
#pragma unroll
            for (int j = 0; j < 4; ++j) acc[i][j] = fmaf(av[i], bv[j], acc[i][j]);
    }
    __syncthreads();
#pragma unroll
    for (int j = 0; j < 4; ++j) {
        const float4 w0 = make_float4(frelu(acc[0][j]), frelu(acc[1][j]),
                                      frelu(acc[2][j]), frelu(acc[3][j]));
        const float4 w1 = make_float4(frelu(acc[4][j]), frelu(acc[5][j]),
                                      frelu(acc[6][j]), frelu(acc[7][j]));
        *(float4*)&sAT[(j0 + j) * PITCH + le0] = w0;
        *(float4*)&sAT[(j0 + j) * PITCH + le0 + 4] = w1;
    }
    __syncthreads();
#pragma unroll
    for (int i = 0; i < 8; ++i)
#pragma unroll
        for (int j = 0; j < 4; ++j) acc[i][j] = sB2[j0 + j];
    for (int k = 0; k < HID; ++k) {
        const float4 b  = *(const float4*)&sW2[k * HID + j0];
        const float4 a0 = *(const float4*)&sAT[k * PITCH + le0];
        const float4 a1 = *(const float4*)&sAT[k * PITCH + le0 + 4];
        const float av[8] = {a0.x, a0.y, a0.z, a0.w, a1.x, a1.y, a1.z, a1.w};
        const float bv[4] = {b.x, b.y, b.z, b.w};
#pragma unroll
        for (int i = 0; i < 8; ++i)
#pragma unroll
            for (int j = 0; j < 4; ++j) acc[i][j] = fmaf(av[i], bv[j], acc[i][j]);
    }
#pragma unroll
    for (int i = 0; i < 8; ++i) {
        const int dst = sDst[le0 + i];
        float* ap = agg + (size_t)dst * HID + j0;
#pragma unroll
        for (int j = 0; j < 4; ++j) atomicAdd(ap + j, acc[i][j]);
    }
}

// -------------------- BN stats: per-channel sum & sumsq over nodes --------------------
__global__ __launch_bounds__(256) void k_bnstats(const float* __restrict__ agg,
    float* __restrict__ stats)
{
    const int c = threadIdx.x & 63;
    const int rg = threadIdx.x >> 6;
    float s = 0.f, ss = 0.f;
    for (size_t n = (size_t)blockIdx.x * 4 + rg; n < NN; n += (size_t)gridDim.x * 4) {
        const float v = agg[n * HID + c];
        s += v;
        ss = fmaf(v, v, ss);
    }
    __shared__ float rs[4][64];
    __shared__ float rss[4][64];
    rs[rg][c] = s; rss[rg][c] = ss;
    __syncthreads();
    if (rg == 0) {
        s  = rs[0][c] + rs[1][c] + rs[2][c] + rs[3][c];
        ss = rss[0][c] + rss[1][c] + rss[2][c] + rss[3][c];
        atomicAdd(&stats[c], s);
        atomicAdd(&stats[64 + c], ss);
    }
}

// -------------------- h += relu(BN(agg)) --------------------
__global__ __launch_bounds__(256) void k_update(const float* __restrict__ agg,
    const float* __restrict__ stats, const float* __restrict__ gamma,
    const float* __restrict__ beta, float* __restrict__ h)
{
    const size_t i = (size_t)blockIdx.x * 256 + threadIdx.x;
    const int c = (int)(i & 63);
    const float mu  = stats[c] * (1.f / NN);
    const float var = fmaf(-mu, mu, stats[64 + c] * (1.f / NN));
    const float inv = rsqrtf(var + BNEPS);
    const float v = fmaf((agg[i] - mu) * inv, gamma[c], beta[c]);
    h[i] += frelu(v);
}

// -------------------- out = relu(h @ W3 + b3) @ W4 + b4 --------------------
__global__ __launch_bounds__(256) void k_out(const float* __restrict__ h,
    const float* __restrict__ W3, const float* __restrict__ b3,
    const float* __restrict__ W4, const float* __restrict__ b4,
    float* __restrict__ out)
{
    __shared__ float sAT[64 * PITCH];
    __shared__ float sW3[HID * HID];
    __shared__ float sW4[HID * 4];
    __shared__ float sB3[HID];
    __shared__ float sB4[4];
    const int t = threadIdx.x;
    const size_t n0 = (size_t)blockIdx.x * 128;

    for (int i = t; i < HID * HID; i += 256) sW3[i] = W3[i];
    if (t < HID * ODD) sW4[(t / ODD) * 4 + (t % ODD)] = W4[t];
    if (t < HID) sB3[t] = b3[t];
    if (t < ODD) sB4[t] = b4[t];

    {
        const int e = t >> 1, half = t & 1;
        const size_t n = n0 + e;
        if (n < NN) {
            const float* hp = h + n * HID + half * 32;
#pragma unroll
            for (int k = 0; k < 32; k += 4) {
                const float4 v = *(const float4*)(hp + k);
                sAT[(half * 32 + k + 0) * PITCH + e] = v.x;
                sAT[(half * 32 + k + 1) * PITCH + e] = v.y;
                sAT[(half * 32 + k + 2) * PITCH + e] = v.z;
                sAT[(half * 32 + k + 3) * PITCH + e] = v.w;
            }
        } else {
#pragma unroll
            for (int k = 0; k < 32; ++k) sAT[(half * 32 + k) * PITCH + e] = 0.f;
        }
    }
    __syncthreads();

    const int og = t & 15, eg = t >> 4;
    const int j0 = og * 4, le0 = eg * 8;
    float acc[8][4];
#pragma unroll
    for (int i = 0; i < 8; ++i)
#pragma unroll
        for (int j = 0; j < 4; ++j) acc[i][j] = sB3[j0 + j];

    for (int k = 0; k < HID; ++k) {
        const float4 b  = *(const float4*)&sW3[k * HID + j0];
        const float4 a0 = *(const float4*)&sAT[k * PITCH + le0];
        const float4 a1 = *(const float4*)&sAT[k * PITCH + le0 + 4];
        const float av[8] = {a0.x, a0.y, a0.z, a0.w, a1.x, a1.y, a1.z, a1.w};
        const float bv[4] = {b.x, b.y, b.z, b.w};
#pragma unroll
        for (int i = 0; i < 8; ++i)
#pragma unroll
            for (int j = 0; j < 4; ++j) acc[i][j] = fmaf(av[i], bv[j], acc[i][j]);
    }
    __syncthreads();

#pragma unroll
    for (int j = 0; j < 4; ++j) {
        const float4 w0 = make_float4(frelu(acc[0][j]), frelu(acc[1][j]),
                                      frelu(acc[2][j]), frelu(acc[3][j]));
        const float4 w1 = make_float4(frelu(acc[4][j]), frelu(acc[5][j]),
                                      frelu(acc[6][j]), frelu(acc[7][j]));
        *(float4*)&sAT[(j0 + j) * PITCH + le0] = w0;
        *(float4*)&sAT[(j0 + j) * PITCH + le0 + 4] = w1;
    }
    __syncthreads();

    if (t < 128) {
        const size_t n = n0 + t;
        if (n < NN) {
            float o[3] = {sB4[0], sB4[1], sB4[2]};
            for (int k = 0; k < HID; ++k) {
                const float v = sAT[k * PITCH + t];
                o[0] = fmaf(v, sW4[k * 4 + 0], o[0]);
                o[1] = fmaf(v, sW4[k * 4 + 1], o[1]);
                o[2] = fmaf(v, sW4[k * 4 + 2], o[2]);
            }
            out[n * 3 + 0] = o[0];
            out[n * 3 + 1] = o[1];
            out[n * 3 + 2] = o[2];
        }
    }
}

extern "C" void kernel_launch(void* const* d_in, const int* in_sizes, int n_in,
                              void* d_out, int out_size, void* d_ws, size_t ws_size,
                              hipStream_t stream)
{
    const float* x   = (const float*)d_in[0];
    const int*   ei  = (const int*)d_in[1];
    const float* ea  = (const float*)d_in[2];
    const float* Win = (const float*)d_in[3];
    const float* bin = (const float*)d_in[4];
    const float* W1  = (const float*)d_in[5];
    const float* b1  = (const float*)d_in[6];
    const float* W2  = (const float*)d_in[7];
    const float* b2  = (const float*)d_in[8];
    const float* gam = (const float*)d_in[9];
    const float* bet = (const float*)d_in[10];
    const float* W3  = (const float*)d_in[11];
    const float* b3  = (const float*)d_in[12];
    const float* W4  = (const float*)d_in[13];
    const float* b4  = (const float*)d_in[14];
    float* out = (float*)d_out;

    // workspace layout
    float* h     = (float*)d_ws;                     // NN*HID
    float* agg   = h + (size_t)NN * HID;             // NN*HID
    float* stats = agg + (size_t)NN * HID;           // 128
    int* deg      = (int*)(stats + 128);             // NN
    int* rowstart = deg + NN;                        // NN+1
    int* cursor   = rowstart + NN + 1;               // NN
    int* bsum     = cursor + NN;                     // 512
    int* bpre     = bsum + 512;                      // 512
    int* eperm    = bpre + 512;                      // EE
    size_t fixed_bytes = (size_t)((char*)(eperm + EE) - (char*)d_ws);
    size_t m_off = (fixed_bytes + 15) & ~(size_t)15;
    float* m = (float*)((char*)d_ws + m_off);

    long mcap = 0;
    if (ws_size > m_off + 1024)
        mcap = (long)((ws_size - m_off) / (HID * sizeof(float)));
    mcap = mcap / EPB * EPB;
    if (mcap > 400000) mcap = 400000;               // keep chunk L3-resident
    const bool sorted_path = (mcap >= 100000);

    k_input<<<NN / 32, 256, 0, stream>>>(x, Win, bin, h);

    if (sorted_path) {
        hipMemsetAsync(deg, 0, (size_t)NN * sizeof(int), stream);
        k_hist<<<(EE + 255) / 256, 256, 0, stream>>>(ei, deg);
        k_part<<<NB, 256, 0, stream>>>(deg, bsum);
        k_top<<<1, 64, 0, stream>>>(bsum, bpre);
        k_scan_add<<<NB, 256, 0, stream>>>(deg, bpre, rowstart, cursor);
        k_permute<<<(EE + 255) / 256, 256, 0, stream>>>(ei, cursor, eperm);

        for (int l = 0; l < NL; ++l) {
            hipMemsetAsync(agg, 0, ((size_t)NN * HID + 128) * sizeof(float), stream);
            const float* lW1 = W1 + (size_t)l * (HID + EDD) * HID;
            const float* lb1 = b1 + (size_t)l * HID;
            const float* lW2 = W2 + (size_t)l * HID * HID;
            const float* lb2 = b2 + (size_t)l * HID;
            for (long i0 = 0; i0 < EE; i0 += mcap) {
                const long i1 = (i0 + mcap < EE) ? i0 + mcap : EE;
                const long ce = i1 - i0;                      // multiple of EPB
                k_mlp<<<(int)(ce / EPB), 256, 0, stream>>>(h, ei, ea, eperm,
                    lW1, lb1, lW2, lb2, m, (int)i0);
                k_agg<<<NN / 4, 256, 0, stream>>>(m, rowstart, agg, (int)i0, (int)i1);
            }
            k_bnstats<<<512, 256, 0, stream>>>(agg, stats);
            k_update<<<(NN * HID) / 256, 256, 0, stream>>>(agg, stats,
                gam + (size_t)l * HID, bet + (size_t)l * HID, h);
        }
    } else {
        // fallback: verified atomic-scatter path
        for (int l = 0; l < NL; ++l) {
            hipMemsetAsync(agg, 0, ((size_t)NN * HID + 128) * sizeof(float), stream);
            k_edge<<<EE / EPB, 256, 0, stream>>>(h, ei, ea,
                W1 + (size_t)l * (HID + EDD) * HID, b1 + (size_t)l * HID,
                W2 + (size_t)l * HID * HID, b2 + (size_t)l * HID, agg);
            k_bnstats<<<512, 256, 0, stream>>>(agg, stats);
            k_update<<<(NN * HID) / 256, 256, 0, stream>>>(agg, stats,
                gam + (size_t)l * HID, bet + (size_t)l * HID, h);
        }
    }

    k_out<<<(NN + 127) / 128, 256, 0, stream>>>(h, W3, b3, W4, b4, out);
}

// Round 8
// 1598.150 us; speedup vs baseline: 2.7976x; 1.3526x over previous
//
#include <hip/hip_runtime.h>

#define NN 100000
#define EE 1600000
#define IND 5
#define HID 64
#define EDD 4
#define ODD 3
#define NL 3
#define BNEPS 1e-5f

#define EPB 128      // edges per block
#define PITCH 132    // f32 LDS pitch (fallback/out kernels)
#define NB 391       // ceil(NN/256)
#define WFRAG 20480  // shorts per layer of pre-split weights

typedef short bf16x8 __attribute__((ext_vector_type(8)));
typedef float f32x4  __attribute__((ext_vector_type(4)));

__device__ __forceinline__ float frelu(float v) { return fmaxf(v, 0.f); }

__device__ __forceinline__ unsigned short f2bf(float f) {
    unsigned u = __float_as_uint(f);
    u += 0x7fffu + ((u >> 16) & 1u);          // RNE
    return (unsigned short)(u >> 16);
}
__device__ __forceinline__ float bf2f(unsigned short b) {
    return __uint_as_float((unsigned)b << 16);
}
// split a,b into packed hi / packed lo bf16 pairs
__device__ __forceinline__ void split2(float a, float b, unsigned& hi, unsigned& lo) {
    const unsigned short ah = f2bf(a), bh = f2bf(b);
    const float ar = a - bf2f(ah);
    const float br = b - bf2f(bh);
    hi = (unsigned)ah | ((unsigned)bh << 16);
    lo = (unsigned)f2bf(ar) | ((unsigned)f2bf(br) << 16);
}

__device__ __forceinline__ int ei_shift(const int* ei32) {
    return ((ei32[1] == 0) && (ei32[3] == 0)) ? 1 : 0;   // int64 detection
}

// -------------------- h0 = relu(x @ Win + bin) --------------------
__global__ __launch_bounds__(256) void k_input(const float* __restrict__ x,
    const float* __restrict__ Win, const float* __restrict__ bin,
    float* __restrict__ h)
{
    __shared__ float sX[32 * IND];
    __shared__ float sW[IND * HID];
    __shared__ float sB[HID];
    const int t = threadIdx.x;
    const int n0 = blockIdx.x * 32;
    if (t < 32 * IND) sX[t] = x[(size_t)n0 * IND + t];
    for (int i = t; i < IND * HID; i += 256) sW[i] = Win[i];
    if (t < HID) sB[t] = bin[t];
    __syncthreads();
    const int nl = t >> 3;
    const int j0 = (t & 7) * 8;
    float acc[8];
#pragma unroll
    for (int j = 0; j < 8; ++j) acc[j] = sB[j0 + j];
#pragma unroll
    for (int k = 0; k < IND; ++k) {
        const float xv = sX[nl * IND + k];
#pragma unroll
        for (int j = 0; j < 8; ++j) acc[j] = fmaf(xv, sW[k * HID + j0 + j], acc[j]);
    }
    float* hp = h + (size_t)(n0 + nl) * HID + j0;
#pragma unroll
    for (int j = 0; j < 8; ++j) hp[j] = frelu(acc[j]);
}

// -------------------- CSR build --------------------
__global__ __launch_bounds__(256) void k_hist(const int* __restrict__ ei32,
    int* __restrict__ deg)
{
    const int sh = ei_shift(ei32);
    const int e = blockIdx.x * 256 + threadIdx.x;
    if (e < EE) atomicAdd(&deg[ei32[(size_t)(EE + e) << sh]], 1);
}

__global__ __launch_bounds__(256) void k_part(const int* __restrict__ deg,
    int* __restrict__ bsum)
{
    const int t = threadIdx.x;
    const int i = blockIdx.x * 256 + t;
    int v = (i < NN) ? deg[i] : 0;
#pragma unroll
    for (int off = 32; off > 0; off >>= 1) v += __shfl_down(v, off, 64);
    __shared__ int wsum[4];
    if ((t & 63) == 0) wsum[t >> 6] = v;
    __syncthreads();
    if (t == 0) bsum[blockIdx.x] = wsum[0] + wsum[1] + wsum[2] + wsum[3];
}

__global__ void k_top(const int* __restrict__ bsum, int* __restrict__ bpre)
{
    if (threadIdx.x == 0) {
        int run = 0;
        for (int i = 0; i < NB; ++i) { bpre[i] = run; run += bsum[i]; }
    }
}

__global__ __launch_bounds__(256) void k_scan_add(const int* __restrict__ deg,
    const int* __restrict__ bpre, int* __restrict__ rowstart, int* __restrict__ cursor)
{
    __shared__ int sa[256], sb[256];
    const int t = threadIdx.x;
    const int i = blockIdx.x * 256 + t;
    const int v = (i < NN) ? deg[i] : 0;
    sa[t] = v;
    int* src = sa; int* dst = sb;
    for (int off = 1; off < 256; off <<= 1) {
        __syncthreads();
        dst[t] = (t >= off) ? (src[t] + src[t - off]) : src[t];
        int* tmp = src; src = dst; dst = tmp;
    }
    __syncthreads();
    const int excl = src[t] - v;
    if (i < NN) {
        const int rs = bpre[blockIdx.x] + excl;
        rowstart[i] = rs;
        cursor[i] = rs;
    }
    if (i == 0) rowstart[NN] = EE;
}

__global__ __launch_bounds__(256) void k_permute(const int* __restrict__ ei32,
    int* __restrict__ cursor, int* __restrict__ eperm)
{
    const int sh = ei_shift(ei32);
    const int e = blockIdx.x * 256 + threadIdx.x;
    if (e < EE) {
        const int d = ei32[(size_t)(EE + e) << sh];
        const int pos = atomicAdd(&cursor[d], 1);
        eperm[pos] = e;
    }
}

// pos-major gather of src/dst/edge_attr into sorted order
__global__ __launch_bounds__(256) void k_gs(const int* __restrict__ ei32,
    const int* __restrict__ eperm, const float* __restrict__ ea,
    int* __restrict__ srcs, int* __restrict__ dsts, float* __restrict__ eas)
{
    const int sh = ei_shift(ei32);
    const int p = blockIdx.x * 256 + threadIdx.x;
    if (p < EE) {
        const int eid = eperm[p];
        srcs[p] = ei32[(size_t)eid << sh];
        dsts[p] = ei32[(size_t)(EE + eid) << sh];
        *(float4*)(eas + (size_t)p * EDD) = *(const float4*)(ea + (size_t)eid * EDD);
    }
}

// pre-split + pre-swizzle weights into MFMA B-fragment order (hi/lo bf16)
// layout per layer (shorts): [0,6144) W1 hi | [6144,12288) W1 lo
//                            [12288,16384) W2 hi | [16384,20480) W2 lo
__global__ __launch_bounds__(256) void k_wprep(const float* __restrict__ W1,
    const float* __restrict__ W2, unsigned short* __restrict__ gw)
{
    const int l = blockIdx.x;
    const float* w1 = W1 + (size_t)l * (HID + EDD) * HID;
    const float* w2 = W2 + (size_t)l * HID * HID;
    unsigned short* o = gw + (size_t)l * WFRAG;
    for (int idx = threadIdx.x; idx < 6144; idx += 256) {
        const int j = idx & 7, lane = (idx >> 3) & 63, ntkb = idx >> 9;
        const int nt = ntkb & 3, kb = ntkb >> 2;
        const int k = kb * 32 + (lane >> 4) * 8 + j;
        const int n = nt * 16 + (lane & 15);
        const float w = (k < HID + EDD) ? w1[k * HID + n] : 0.f;
        const unsigned short hi = f2bf(w);
        o[idx] = hi;
        o[6144 + idx] = f2bf(w - bf2f(hi));
    }
    for (int idx = threadIdx.x; idx < 4096; idx += 256) {
        const int j = idx & 7, lane = (idx >> 3) & 63, ntkb = idx >> 9;
        const int nt = ntkb & 3, kb = ntkb >> 2;
        const int k = kb * 32 + (lane >> 4) * 8 + j;
        const int n = nt * 16 + (lane & 15);
        const float w = w2[k * HID + n];
        const unsigned short hi = f2bf(w);
        o[12288 + idx] = hi;
        o[16384 + idx] = f2bf(w - bf2f(hi));
    }
}

// ==== fused MFMA edge MLP (split-bf16 precision) + in-block segmented agg ====
__global__ __launch_bounds__(256, 2) void k_mlpf(const float* __restrict__ h,
    const int* __restrict__ srcs, const int* __restrict__ dsts,
    const float* __restrict__ eas, const unsigned short* __restrict__ gw,
    const float* __restrict__ b1, const float* __restrict__ b2,
    float* __restrict__ agg)
{
    // union: A1 hi[128][104]+lo (53.2KB) -> A2 hi[128][72]+lo (36.9KB) -> segbuf f32[128][64] (32KB)
    __shared__ __align__(16) unsigned char uni[53248];
    __shared__ float sB1[64], sB2[64];
    __shared__ int sDst[128];
    __shared__ int sSeg[128];
    __shared__ int sSegNode[128];
    __shared__ int sSegFlag[128];
    __shared__ int sNseg, sDprev, sDnext;

    unsigned short* uA1h = (unsigned short*)uni;            // [128][104]
    unsigned short* uA1l = (unsigned short*)(uni + 26624);  // [128][104]
    unsigned short* uA2h = (unsigned short*)uni;            // [128][72]
    unsigned short* uA2l = (unsigned short*)(uni + 18432);  // [128][72]
    float* segbuf = (float*)uni;                            // [128][64]

    const bf16x8* gW1h = (const bf16x8*)gw;
    const bf16x8* gW1l = (const bf16x8*)(gw + 6144);
    const bf16x8* gW2h = (const bf16x8*)(gw + 12288);
    const bf16x8* gW2l = (const bf16x8*)(gw + 16384);

    const int t = threadIdx.x;
    const int wave = t >> 6, lane = t & 63;
    const int p0 = blockIdx.x * EPB;

    if (t < 64) { sB1[t] = b1[t]; sB2[t] = b2[t]; }
    if (t == 252) sDprev = (p0 > 0) ? dsts[p0 - 1] : -1;
    if (t == 253) sDnext = (p0 + EPB < EE) ? dsts[p0 + EPB] : -1;

    {   // gather h[src] -> split bf16 A1 rows; 2 threads/edge
        const int e = t >> 1, half = t & 1;
        const int p = p0 + e;
        const int src = srcs[p];
        const float4* hp = (const float4*)(h + (size_t)src * HID + half * 32);
        uint4* ah = (uint4*)(uA1h + e * 104 + half * 32);
        uint4* al = (uint4*)(uA1l + e * 104 + half * 32);
#pragma unroll
        for (int i = 0; i < 4; ++i) {
            const float4 v0 = hp[2 * i], v1 = hp[2 * i + 1];
            unsigned h0, l0, h1, l1, h2, l2, h3, l3;
            split2(v0.x, v0.y, h0, l0);
            split2(v0.z, v0.w, h1, l1);
            split2(v1.x, v1.y, h2, l2);
            split2(v1.z, v1.w, h3, l3);
            ah[i] = make_uint4(h0, h1, h2, h3);
            al[i] = make_uint4(l0, l1, l2, l3);
        }
        if (half) {   // edge_attr at k 64..67; ZERO k 68..95 (hi and lo)
            const float4 a = *(const float4*)(eas + (size_t)p * EDD);
            unsigned h0, l0, h1, l1;
            split2(a.x, a.y, h0, l0);
            split2(a.z, a.w, h1, l1);
            uint4* eh = (uint4*)(uA1h + e * 104 + 64);
            uint4* el = (uint4*)(uA1l + e * 104 + 64);
            const uint4 z = make_uint4(0u, 0u, 0u, 0u);
            eh[0] = make_uint4(h0, h1, 0u, 0u);
            eh[1] = z; eh[2] = z; eh[3] = z;
            el[0] = make_uint4(l0, l1, 0u, 0u);
            el[1] = z; el[2] = z; el[3] = z;
        } else {
            sDst[e] = dsts[p];
        }
    }
    __syncthreads();   // (1) A1 + tables ready

    // ---- stage 1: [128 x 96(pad)] @ [96 x 64], 3-term split products ----
    const int er0 = wave * 32;
    const int lrow = lane & 15, lgrp = lane >> 4;
    f32x4 acc1[2][4];
#pragma unroll
    for (int mt = 0; mt < 2; ++mt)
#pragma unroll
        for (int nt = 0; nt < 4; ++nt) {
            const float bv = sB1[nt * 16 + lrow];
            acc1[mt][nt] = (f32x4){bv, bv, bv, bv};
        }
#pragma unroll
    for (int ks = 0; ks < 3; ++ks) {
        bf16x8 aH[2], aL[2];
#pragma unroll
        for (int mt = 0; mt < 2; ++mt) {
            const int off = (er0 + mt * 16 + lrow) * 104 + ks * 32 + lgrp * 8;
            aH[mt] = *(const bf16x8*)&uA1h[off];
            aL[mt] = *(const bf16x8*)&uA1l[off];
        }
#pragma unroll
        for (int nt = 0; nt < 4; ++nt) {
            const int fi = (ks * 4 + nt) * 64 + lane;
            const bf16x8 bH = gW1h[fi];
            const bf16x8 bL = gW1l[fi];
#pragma unroll
            for (int mt = 0; mt < 2; ++mt) {
                acc1[mt][nt] = __builtin_amdgcn_mfma_f32_16x16x32_bf16(aH[mt], bH, acc1[mt][nt], 0, 0, 0);
                acc1[mt][nt] = __builtin_amdgcn_mfma_f32_16x16x32_bf16(aH[mt], bL, acc1[mt][nt], 0, 0, 0);
                acc1[mt][nt] = __builtin_amdgcn_mfma_f32_16x16x32_bf16(aL[mt], bH, acc1[mt][nt], 0, 0, 0);
            }
        }
    }
    __syncthreads();   // (2) all A1 reads done; union rewritable

    // ---- relu + split, D-frag -> A2[edge][k2] ----
#pragma unroll
    for (int mt = 0; mt < 2; ++mt)
#pragma unroll
        for (int nt = 0; nt < 4; ++nt)
#pragma unroll
            for (int r = 0; r < 4; ++r) {
                const int edge = er0 + mt * 16 + lgrp * 4 + r;
                const float v = fmaxf(acc1[mt][nt][r], 0.f);
                const unsigned short hi = f2bf(v);
                uA2h[edge * 72 + nt * 16 + lrow] = hi;
                uA2l[edge * 72 + nt * 16 + lrow] = f2bf(v - bf2f(hi));
            }

    // ---- segmentation (wave 0): ballot scan over 128 start flags ----
    if (wave == 0) {
        const int e0 = lane, e1 = lane + 64;
        const int d0 = sDst[e0], d1 = sDst[e1];
        const int f0 = (e0 == 0) ? 1 : (d0 != sDst[e0 - 1] ? 1 : 0);
        const int f1 = (d1 != sDst[e1 - 1]) ? 1 : 0;
        const unsigned long long m0 = __ballot(f0);
        const unsigned long long m1 = __ballot(f1);
        const unsigned long long below = (1ull << lane) - 1ull;
        const int c0 = __popcll(m0);
        const int s0 = __popcll(m0 & below) + f0 - 1;
        const int s1 = c0 + __popcll(m1 & below) + f1 - 1;
        sSeg[e0] = s0; sSeg[e1] = s1;
        if (f0) sSegNode[s0] = d0;
        if (f1) sSegNode[s1] = d1;
        const int nseg = c0 + __popcll(m1);
        if (lane == 0) sNseg = nseg;
#pragma unroll
        for (int hh = 0; hh < 2; ++hh) {
            const int s = lane + hh * 64;
            if (s < nseg) {
                int fl = 1;
                if (s == 0) fl &= (sDst[0] != sDprev) ? 1 : 0;
                if (s == nseg - 1) fl &= (sDst[127] != sDnext) ? 1 : 0;
                sSegFlag[s] = fl;
            }
        }
    }
    __syncthreads();   // (3) A2 + seg tables visible to all

    // ---- stage 2: [128 x 64] @ [64 x 64], 3-term split products ----
    f32x4 acc2[2][4];
#pragma unroll
    for (int mt = 0; mt < 2; ++mt)
#pragma unroll
        for (int nt = 0; nt < 4; ++nt) {
            const float bv = sB2[nt * 16 + lrow];
            acc2[mt][nt] = (f32x4){bv, bv, bv, bv};
        }
#pragma unroll
    for (int ks = 0; ks < 2; ++ks) {
        bf16x8 aH[2], aL[2];
#pragma unroll
        for (int mt = 0; mt < 2; ++mt) {
            const int off = (er0 + mt * 16 + lrow) * 72 + ks * 32 + lgrp * 8;
            aH[mt] = *(const bf16x8*)&uA2h[off];
            aL[mt] = *(const bf16x8*)&uA2l[off];
        }
#pragma unroll
        for (int nt = 0; nt < 4; ++nt) {
            const int fi = (ks * 4 + nt) * 64 + lane;
            const bf16x8 bH = gW2h[fi];
            const bf16x8 bL = gW2l[fi];
#pragma unroll
            for (int mt = 0; mt < 2; ++mt) {
                acc2[mt][nt] = __builtin_amdgcn_mfma_f32_16x16x32_bf16(aH[mt], bH, acc2[mt][nt], 0, 0, 0);
                acc2[mt][nt] = __builtin_amdgcn_mfma_f32_16x16x32_bf16(aH[mt], bL, acc2[mt][nt], 0, 0, 0);
                acc2[mt][nt] = __builtin_amdgcn_mfma_f32_16x16x32_bf16(aL[mt], bH, acc2[mt][nt], 0, 0, 0);
            }
        }
    }
    __syncthreads();   // (4) A2 reads done; union becomes segbuf

    {   // zero segbuf
        const float4 z = make_float4(0.f, 0.f, 0.f, 0.f);
        float4* sb4 = (float4*)segbuf;
        for (int i = t; i < 2048; i += 256) sb4[i] = z;
    }
    __syncthreads();   // (5)

    // ---- LDS segmented accumulate (run-merged) ----
#pragma unroll
    for (int mt = 0; mt < 2; ++mt) {
        int sg[4];
#pragma unroll
        for (int r = 0; r < 4; ++r) sg[r] = sSeg[er0 + mt * 16 + lgrp * 4 + r];
#pragma unroll
        for (int nt = 0; nt < 4; ++nt) {
            const int col = nt * 16 + lrow;
            float rv = acc2[mt][nt][0];
            int cs = sg[0];
#pragma unroll
            for (int r = 1; r < 4; ++r) {
                if (sg[r] == cs) rv += acc2[mt][nt][r];
                else { atomicAdd(&segbuf[cs * 64 + col], rv); cs = sg[r]; rv = acc2[mt][nt][r]; }
            }
            atomicAdd(&segbuf[cs * 64 + col], rv);
        }
    }
    __syncthreads();   // (6)

    // ---- write out: interior segs plain store, boundary segs atomic ----
    const int nseg = sNseg;
    for (int s = wave; s < nseg; s += 4) {
        const float v = segbuf[s * 64 + lane];
        float* ap = agg + (size_t)sSegNode[s] * HID + lane;
        if (sSegFlag[s]) *ap = v;
        else atomicAdd(ap, v);
    }
}

// ---- fallback path (atomic scatter), used only if ws_size is too small ----
__global__ __launch_bounds__(256) void k_edge(const float* __restrict__ h,
    const int* __restrict__ ei32, const float* __restrict__ ea,
    const float* __restrict__ W1, const float* __restrict__ b1,
    const float* __restrict__ W2, const float* __restrict__ b2,
    float* __restrict__ agg)
{
    __shared__ float sAT[68 * PITCH];
    __shared__ float sW1[68 * HID];
    __shared__ float sW2[HID * HID];
    __shared__ float sB1[HID];
    __shared__ float sB2[HID];
    __shared__ int   sDst[EPB];
    const int t = threadIdx.x;
    const size_t e0 = (size_t)blockIdx.x * EPB;
    const int sh = ei_shift(ei32);

    for (int i = t; i < 68 * HID; i += 256) sW1[i] = W1[i];
    for (int i = t; i < HID * HID; i += 256) sW2[i] = W2[i];
    if (t < HID) { sB1[t] = b1[t]; sB2[t] = b2[t]; }
    if (t < EPB) sDst[t] = ei32[(EE + e0 + t) << sh];

    {
        const int e = t >> 1, half = t & 1;
        const int src = ei32[(e0 + e) << sh];
        const float* hp = h + (size_t)src * HID + half * 32;
#pragma unroll
        for (int k = 0; k < 32; k += 4) {
            const float4 v = *(const float4*)(hp + k);
            sAT[(half * 32 + k + 0) * PITCH + e] = v.x;
            sAT[(half * 32 + k + 1) * PITCH + e] = v.y;
            sAT[(half * 32 + k + 2) * PITCH + e] = v.z;
            sAT[(half * 32 + k + 3) * PITCH + e] = v.w;
        }
        if (half) {
            const float4 a = *(const float4*)(ea + (e0 + e) * EDD);
            sAT[(64 + 0) * PITCH + e] = a.x;
            sAT[(64 + 1) * PITCH + e] = a.y;
            sAT[(64 + 2) * PITCH + e] = a.z;
            sAT[(64 + 3) * PITCH + e] = a.w;
        }
    }
    __syncthreads();

    const int og = t & 15, eg = t >> 4;
    const int j0 = og * 4, le0 = eg * 8;
    float acc[8][4];
#pragma unroll
    for (int i = 0; i < 8; ++i)
#pragma unroll
        for (int j = 0; j < 4; ++j) acc[i][j] = sB1[j0 + j];
    for (int k = 0; k < 68; ++k) {
        const float4 b  = *(const float4*)&sW1[k * HID + j0];
        const float4 a0 = *(const float4*)&sAT[k * PITCH + le0];
        const float4 a1 = *(const float4*)&sAT[k * PITCH + le0 + 4];
        const float av[8] = {a0.x, a0.y, a0.z, a0.w, a1.x, a1.y, a1.z, a1.w};
        const float bv[4] = {b.x, b.y, b.z, b.w};
#pragma unroll
        for (int i = 0; i < 8; ++i)
#pragma unroll
            for (int j = 0; j < 4; ++j) acc[i][j] = fmaf(av[i], bv[j], acc[i][j]);
    }
    __syncthreads();
#pragma unroll
    for (int j = 0; j < 4; ++j) {
        const float4 w0 = make_float4(frelu(acc[0][j]), frelu(acc[1][j]),
                                      frelu(acc[2][j]), frelu(acc[3][j]));
        const float4 w1 = make_float4(frelu(acc[4][j]), frelu(acc[5][j]),
                                      frelu(acc[6][j]), frelu(acc[7][j]));
        *(float4*)&sAT[(j0 + j) * PITCH + le0] = w0;
        *(float4*)&sAT[(j0 + j) * PITCH + le0 + 4] = w1;
    }
    __syncthreads();
#pragma unroll
    for (int i = 0; i < 8; ++i)
#pragma unroll
        for (int j = 0; j < 4; ++j) acc[i][j] = sB2[j0 + j];
    for (int k = 0; k < HID; ++k) {
        const float4 b  = *(const float4*)&sW2[k * HID + j0];
        const float4 a0 = *(const float4*)&sAT[k * PITCH + le0];
        const float4 a1 = *(const float4*)&sAT[k * PITCH + le0 + 4];
        const float av[8] = {a0.x, a0.y, a0.z, a0.w, a1.x, a1.y, a1.z, a1.w};
        const float bv[4] = {b.x, b.y, b.z, b.w};
#pragma unroll
        for (int i = 0; i < 8; ++i)
#pragma unroll
            for (int j = 0; j < 4; ++j) acc[i][j] = fmaf(av[i], bv[j], acc[i][j]);
    }
#pragma unroll
    for (int i = 0; i < 8; ++i) {
        const int dst = sDst[le0 + i];
        float* ap = agg + (size_t)dst * HID + j0;
#pragma unroll
        for (int j = 0; j < 4; ++j) atomicAdd(ap + j, acc[i][j]);
    }
}

// -------------------- BN stats --------------------
__global__ __launch_bounds__(256) void k_bnstats(const float* __restrict__ agg,
    float* __restrict__ stats)
{
    const int c = threadIdx.x & 63;
    const int rg = threadIdx.x >> 6;
    float s = 0.f, ss = 0.f;
    for (size_t n = (size_t)blockIdx.x * 4 + rg; n < NN; n += (size_t)gridDim.x * 4) {
        const float v = agg[n * HID + c];
        s += v;
        ss = fmaf(v, v, ss);
    }
    __shared__ float rs[4][64];
    __shared__ float rss[4][64];
    rs[rg][c] = s; rss[rg][c] = ss;
    __syncthreads();
    if (rg == 0) {
        s  = rs[0][c] + rs[1][c] + rs[2][c] + rs[3][c];
        ss = rss[0][c] + rss[1][c] + rss[2][c] + rss[3][c];
        atomicAdd(&stats[c], s);
        atomicAdd(&stats[64 + c], ss);
    }
}

// -------------------- h += relu(BN(agg)) --------------------
__global__ __launch_bounds__(256) void k_update(const float* __restrict__ agg,
    const float* __restrict__ stats, const float* __restrict__ gamma,
    const float* __restrict__ beta, float* __restrict__ h)
{
    const size_t i = (size_t)blockIdx.x * 256 + threadIdx.x;
    const int c = (int)(i & 63);
    const float mu  = stats[c] * (1.f / NN);
    const float var = fmaf(-mu, mu, stats[64 + c] * (1.f / NN));
    const float inv = rsqrtf(var + BNEPS);
    const float v = fmaf((agg[i] - mu) * inv, gamma[c], beta[c]);
    h[i] += frelu(v);
}

// -------------------- out = relu(h @ W3 + b3) @ W4 + b4 --------------------
__global__ __launch_bounds__(256) void k_out(const float* __restrict__ h,
    const float* __restrict__ W3, const float* __restrict__ b3,
    const float* __restrict__ W4, const float* __restrict__ b4,
    float* __restrict__ out)
{
    __shared__ float sAT[64 * PITCH];
    __shared__ float sW3[HID * HID];
    __shared__ float sW4[HID * 4];
    __shared__ float sB3[HID];
    __shared__ float sB4[4];
    const int t = threadIdx.x;
    const size_t n0 = (size_t)blockIdx.x * 128;

    for (int i = t; i < HID * HID; i += 256) sW3[i] = W3[i];
    if (t < HID * ODD) sW4[(t / ODD) * 4 + (t % ODD)] = W4[t];
    if (t < HID) sB3[t] = b3[t];
    if (t < ODD) sB4[t] = b4[t];

    {
        const int e = t >> 1, half = t & 1;
        const size_t n = n0 + e;
        if (n < NN) {
            const float* hp = h + n * HID + half * 32;
#pragma unroll
            for (int k = 0; k < 32; k += 4) {
                const float4 v = *(const float4*)(hp + k);
                sAT[(half * 32 + k + 0) * PITCH + e] = v.x;
                sAT[(half * 32 + k + 1) * PITCH + e] = v.y;
                sAT[(half * 32 + k + 2) * PITCH + e] = v.z;
                sAT[(half * 32 + k + 3) * PITCH + e] = v.w;
            }
        } else {
#pragma unroll
            for (int k = 0; k < 32; ++k) sAT[(half * 32 + k) * PITCH + e] = 0.f;
        }
    }
    __syncthreads();

    const int og = t & 15, eg = t >> 4;
    const int j0 = og * 4, le0 = eg * 8;
    float acc[8][4];
#pragma unroll
    for (int i = 0; i < 8; ++i)
#pragma unroll
        for (int j = 0; j < 4; ++j) acc[i][j] = sB3[j0 + j];

    for (int k = 0; k < HID; ++k) {
        const float4 b  = *(const float4*)&sW3[k * HID + j0];
        const float4 a0 = *(const float4*)&sAT[k * PITCH + le0];
        const float4 a1 = *(const float4*)&sAT[k * PITCH + le0 + 4];
        const float av[8] = {a0.x, a0.y, a0.z, a0.w, a1.x, a1.y, a1.z, a1.w};
        const float bv[4] = {b.x, b.y, b.z, b.w};
#pragma unroll
        for (int i = 0; i < 8; ++i)
#pragma unroll
            for (int j = 0; j < 4; ++j) acc[i][j] = fmaf(av[i], bv[j], acc[i][j]);
    }
    __syncthreads();

#pragma unroll
    for (int j = 0; j < 4; ++j) {
        const float4 w0 = make_float4(frelu(acc[0][j]), frelu(acc[1][j]),
                                      frelu(acc[2][j]), frelu(acc[3][j]));
        const float4 w1 = make_float4(frelu(acc[4][j]), frelu(acc[5][j]),
                                      frelu(acc[6][j]), frelu(acc[7][j]));
        *(float4*)&sAT[(j0 + j) * PITCH + le0] = w0;
        *(float4*)&sAT[(j0 + j) * PITCH + le0 + 4] = w1;
    }
    __syncthreads();

    if (t < 128) {
        const size_t n = n0 + t;
        if (n < NN) {
            float o[3] = {sB4[0], sB4[1], sB4[2]};
            for (int k = 0; k < HID; ++k) {
                const float v = sAT[k * PITCH + t];
                o[0] = fmaf(v, sW4[k * 4 + 0], o[0]);
                o[1] = fmaf(v, sW4[k * 4 + 1], o[1]);
                o[2] = fmaf(v, sW4[k * 4 + 2], o[2]);
            }
            out[n * 3 + 0] = o[0];
            out[n * 3 + 1] = o[1];
            out[n * 3 + 2] = o[2];
        }
    }
}

extern "C" void kernel_launch(void* const* d_in, const int* in_sizes, int n_in,
                              void* d_out, int out_size, void* d_ws, size_t ws_size,
                              hipStream_t stream)
{
    const float* x   = (const float*)d_in[0];
    const int*   ei  = (const int*)d_in[1];
    const float* ea  = (const float*)d_in[2];
    const float* Win = (const float*)d_in[3];
    const float* bin = (const float*)d_in[4];
    const float* W1  = (const float*)d_in[5];
    const float* b1  = (const float*)d_in[6];
    const float* W2  = (const float*)d_in[7];
    const float* b2  = (const float*)d_in[8];
    const float* gam = (const float*)d_in[9];
    const float* bet = (const float*)d_in[10];
    const float* W3  = (const float*)d_in[11];
    const float* b3  = (const float*)d_in[12];
    const float* W4  = (const float*)d_in[13];
    const float* b4  = (const float*)d_in[14];
    float* out = (float*)d_out;

    // workspace layout (~97 MB)
    float* h     = (float*)d_ws;                     // NN*HID
    float* agg   = h + (size_t)NN * HID;             // NN*HID
    float* stats = agg + (size_t)NN * HID;           // 128
    int* deg      = (int*)(stats + 128);             // NN
    int* rowstart = deg + NN;                        // NN+1
    int* cursor   = rowstart + NN + 1;               // NN
    int* bsum     = cursor + NN;                     // 512
    int* bpre     = bsum + 512;                      // 512
    int* eperm    = bpre + 512;                      // EE
    int* dsts     = eperm + EE;                      // EE
    int* srcs     = dsts + EE;                       // EE
    size_t off = (size_t)((char*)(srcs + EE) - (char*)d_ws);
    off = (off + 15) & ~(size_t)15;
    unsigned short* gw = (unsigned short*)((char*)d_ws + off);   // 3*WFRAG shorts
    off += (size_t)NL * WFRAG * sizeof(unsigned short);
    off = (off + 15) & ~(size_t)15;
    float* eas = (float*)((char*)d_ws + off);                    // EE*EDD floats
    const size_t need = off + (size_t)EE * EDD * sizeof(float);
    const bool sorted_path = (ws_size >= need);

    k_input<<<NN / 32, 256, 0, stream>>>(x, Win, bin, h);

    if (sorted_path) {
        hipMemsetAsync(deg, 0, (size_t)NN * sizeof(int), stream);
        k_hist<<<(EE + 255) / 256, 256, 0, stream>>>(ei, deg);
        k_part<<<NB, 256, 0, stream>>>(deg, bsum);
        k_top<<<1, 64, 0, stream>>>(bsum, bpre);
        k_scan_add<<<NB, 256, 0, stream>>>(deg, bpre, rowstart, cursor);
        k_permute<<<(EE + 255) / 256, 256, 0, stream>>>(ei, cursor, eperm);
        k_gs<<<(EE + 255) / 256, 256, 0, stream>>>(ei, eperm, ea, srcs, dsts, eas);
        k_wprep<<<NL, 256, 0, stream>>>(W1, W2, gw);

        for (int l = 0; l < NL; ++l) {
            hipMemsetAsync(agg, 0, ((size_t)NN * HID + 128) * sizeof(float), stream);
            k_mlpf<<<EE / EPB, 256, 0, stream>>>(h, srcs, dsts, eas,
                gw + (size_t)l * WFRAG, b1 + (size_t)l * HID, b2 + (size_t)l * HID, agg);
            k_bnstats<<<512, 256, 0, stream>>>(agg, stats);
            k_update<<<(NN * HID) / 256, 256, 0, stream>>>(agg, stats,
                gam + (size_t)l * HID, bet + (size_t)l * HID, h);
        }
    } else {
        for (int l = 0; l < NL; ++l) {
            hipMemsetAsync(agg, 0, ((size_t)NN * HID + 128) * sizeof(float), stream);
            k_edge<<<EE / EPB, 256, 0, stream>>>(h, ei, ea,
                W1 + (size_t)l * (HID + EDD) * HID, b1 + (size_t)l * HID,
                W2 + (size_t)l * HID * HID, b2 + (size_t)l * HID, agg);
            k_bnstats<<<512, 256, 0, stream>>>(agg, stats);
            k_update<<<(NN * HID) / 256, 256, 0, stream>>>(agg, stats,
                gam + (size_t)l * HID, bet + (size_t)l * HID, h);
        }
    }

    k_out<<<(NN + 127) / 128, 256, 0, stream>>>(h, W3, b3, W4, b4, out);
}

// Round 11
// 1470.797 us; speedup vs baseline: 3.0398x; 1.0866x over previous
//
#include <hip/hip_runtime.h>

#define NN 100000
#define EE 1600000
#define IND 5
#define HID 64
#define EDD 4
#define ODD 3
#define NL 3
#define BNEPS 1e-5f

#define EPB 128      // edges per block
#define PITCH 132    // f32 LDS pitch (fallback/out kernels)
#define NB 391       // ceil(NN/256)
#define WFRAG 20480  // shorts per layer of pre-split weights
#define AP1 96       // A1 LDS pitch (shorts): k range [0,96), no pad -> 3 blocks/CU

typedef short bf16x8 __attribute__((ext_vector_type(8)));
typedef float f32x4  __attribute__((ext_vector_type(4)));

__device__ __forceinline__ float frelu(float v) { return fmaxf(v, 0.f); }

__device__ __forceinline__ unsigned short f2bf(float f) {
    unsigned u = __float_as_uint(f);
    u += 0x7fffu + ((u >> 16) & 1u);          // RNE
    return (unsigned short)(u >> 16);
}
__device__ __forceinline__ float bf2f(unsigned short b) {
    return __uint_as_float((unsigned)b << 16);
}
// split a,b into packed hi / packed lo bf16 pairs
__device__ __forceinline__ void split2(float a, float b, unsigned& hi, unsigned& lo) {
    const unsigned short ah = f2bf(a), bh = f2bf(b);
    const float ar = a - bf2f(ah);
    const float br = b - bf2f(bh);
    hi = (unsigned)ah | ((unsigned)bh << 16);
    lo = (unsigned)f2bf(ar) | ((unsigned)f2bf(br) << 16);
}

__device__ __forceinline__ int ei_shift(const int* ei32) {
    return ((ei32[1] == 0) && (ei32[3] == 0)) ? 1 : 0;   // int64 detection
}

// -------------------- h0 = relu(x @ Win + bin) --------------------
__global__ __launch_bounds__(256) void k_input(const float* __restrict__ x,
    const float* __restrict__ Win, const float* __restrict__ bin,
    float* __restrict__ h)
{
    __shared__ float sX[32 * IND];
    __shared__ float sW[IND * HID];
    __shared__ float sB[HID];
    const int t = threadIdx.x;
    const int n0 = blockIdx.x * 32;
    if (t < 32 * IND) sX[t] = x[(size_t)n0 * IND + t];
    for (int i = t; i < IND * HID; i += 256) sW[i] = Win[i];
    if (t < HID) sB[t] = bin[t];
    __syncthreads();
    const int nl = t >> 3;
    const int j0 = (t & 7) * 8;
    float acc[8];
#pragma unroll
    for (int j = 0; j < 8; ++j) acc[j] = sB[j0 + j];
#pragma unroll
    for (int k = 0; k < IND; ++k) {
        const float xv = sX[nl * IND + k];
#pragma unroll
        for (int j = 0; j < 8; ++j) acc[j] = fmaf(xv, sW[k * HID + j0 + j], acc[j]);
    }
    float* hp = h + (size_t)(n0 + nl) * HID + j0;
#pragma unroll
    for (int j = 0; j < 8; ++j) hp[j] = frelu(acc[j]);
}

// -------------------- CSR build --------------------
__global__ __launch_bounds__(256) void k_hist(const int* __restrict__ ei32,
    int* __restrict__ deg)
{
    const int sh = ei_shift(ei32);
    const int e = blockIdx.x * 256 + threadIdx.x;
    if (e < EE) atomicAdd(&deg[ei32[(size_t)(EE + e) << sh]], 1);
}

__global__ __launch_bounds__(256) void k_part(const int* __restrict__ deg,
    int* __restrict__ bsum)
{
    const int t = threadIdx.x;
    const int i = blockIdx.x * 256 + t;
    int v = (i < NN) ? deg[i] : 0;
#pragma unroll
    for (int off = 32; off > 0; off >>= 1) v += __shfl_down(v, off, 64);
    __shared__ int wsum[4];
    if ((t & 63) == 0) wsum[t >> 6] = v;
    __syncthreads();
    if (t == 0) bsum[blockIdx.x] = wsum[0] + wsum[1] + wsum[2] + wsum[3];
}

__global__ void k_top(const int* __restrict__ bsum, int* __restrict__ bpre)
{
    if (threadIdx.x == 0) {
        int run = 0;
        for (int i = 0; i < NB; ++i) { bpre[i] = run; run += bsum[i]; }
    }
}

__global__ __launch_bounds__(256) void k_scan_add(const int* __restrict__ deg,
    const int* __restrict__ bpre, int* __restrict__ rowstart, int* __restrict__ cursor)
{
    __shared__ int sa[256], sb[256];
    const int t = threadIdx.x;
    const int i = blockIdx.x * 256 + t;
    const int v = (i < NN) ? deg[i] : 0;
    sa[t] = v;
    int* src = sa; int* dst = sb;
    for (int off = 1; off < 256; off <<= 1) {
        __syncthreads();
        dst[t] = (t >= off) ? (src[t] + src[t - off]) : src[t];
        int* tmp = src; src = dst; dst = tmp;
    }
    __syncthreads();
    const int excl = src[t] - v;
    if (i < NN) {
        const int rs = bpre[blockIdx.x] + excl;
        rowstart[i] = rs;
        cursor[i] = rs;
    }
    if (i == 0) rowstart[NN] = EE;
}

__global__ __launch_bounds__(256) void k_permute(const int* __restrict__ ei32,
    int* __restrict__ cursor, int* __restrict__ eperm)
{
    const int sh = ei_shift(ei32);
    const int e = blockIdx.x * 256 + threadIdx.x;
    if (e < EE) {
        const int d = ei32[(size_t)(EE + e) << sh];
        const int pos = atomicAdd(&cursor[d], 1);
        eperm[pos] = e;
    }
}

// pos-major gather of src/dst/edge_attr into sorted order
__global__ __launch_bounds__(256) void k_gs(const int* __restrict__ ei32,
    const int* __restrict__ eperm, const float* __restrict__ ea,
    int* __restrict__ srcs, int* __restrict__ dsts, float* __restrict__ eas)
{
    const int sh = ei_shift(ei32);
    const int p = blockIdx.x * 256 + threadIdx.x;
    if (p < EE) {
        const int eid = eperm[p];
        srcs[p] = ei32[(size_t)eid << sh];
        dsts[p] = ei32[(size_t)(EE + eid) << sh];
        *(float4*)(eas + (size_t)p * EDD) = *(const float4*)(ea + (size_t)eid * EDD);
    }
}

// pre-split + pre-swizzle weights into MFMA B-fragment order (hi/lo bf16)
// layout per layer (shorts): [0,6144) W1 hi | [6144,12288) W1 lo
//                            [12288,16384) W2 hi | [16384,20480) W2 lo
__global__ __launch_bounds__(256) void k_wprep(const float* __restrict__ W1,
    const float* __restrict__ W2, unsigned short* __restrict__ gw)
{
    const int l = blockIdx.x;
    const float* w1 = W1 + (size_t)l * (HID + EDD) * HID;
    const float* w2 = W2 + (size_t)l * HID * HID;
    unsigned short* o = gw + (size_t)l * WFRAG;
    for (int idx = threadIdx.x; idx < 6144; idx += 256) {
        const int j = idx & 7, lane = (idx >> 3) & 63, ntkb = idx >> 9;
        const int nt = ntkb & 3, kb = ntkb >> 2;
        const int k = kb * 32 + (lane >> 4) * 8 + j;
        const int n = nt * 16 + (lane & 15);
        const float w = (k < HID + EDD) ? w1[k * HID + n] : 0.f;
        const unsigned short hi = f2bf(w);
        o[idx] = hi;
        o[6144 + idx] = f2bf(w - bf2f(hi));
    }
    for (int idx = threadIdx.x; idx < 4096; idx += 256) {
        const int j = idx & 7, lane = (idx >> 3) & 63, ntkb = idx >> 9;
        const int nt = ntkb & 3, kb = ntkb >> 2;
        const int k = kb * 32 + (lane >> 4) * 8 + j;
        const int n = nt * 16 + (lane & 15);
        const float w = w2[k * HID + n];
        const unsigned short hi = f2bf(w);
        o[12288 + idx] = hi;
        o[16384 + idx] = f2bf(w - bf2f(hi));
    }
}

// ==== fused MFMA edge MLP (split-bf16) + in-block segmented agg ====
// 256 thr = 4 waves; A1 pitch 96 (no pad) -> LDS ~51.7KB -> 3 blocks/CU
__global__ __launch_bounds__(256, 3) void k_mlpf(const float* __restrict__ h,
    const int* __restrict__ srcs, const int* __restrict__ dsts,
    const float* __restrict__ eas, const unsigned short* __restrict__ gw,
    const float* __restrict__ b1, const float* __restrict__ b2,
    float* __restrict__ agg)
{
    // union: A1 hi[128][96]+lo (49.2KB) -> A2 hi[128][72]+lo (36.9KB) -> segbuf f32[128][64] (32KB)
    __shared__ __align__(16) unsigned char uni[49152];
    __shared__ float sB1[64], sB2[64];
    __shared__ int sDst[128];
    __shared__ int sSeg[128];
    __shared__ int sSegNode[128];
    __shared__ int sSegFlag[128];
    __shared__ int sNseg, sDprev, sDnext;

    unsigned short* uA1h = (unsigned short*)uni;            // [128][96]
    unsigned short* uA1l = (unsigned short*)(uni + 24576);  // [128][96]
    unsigned short* uA2h = (unsigned short*)uni;            // [128][72]
    unsigned short* uA2l = (unsigned short*)(uni + 18432);  // [128][72]
    float* segbuf = (float*)uni;                            // [128][64]

    const bf16x8* gW1h = (const bf16x8*)gw;
    const bf16x8* gW1l = (const bf16x8*)(gw + 6144);
    const bf16x8* gW2h = (const bf16x8*)(gw + 12288);
    const bf16x8* gW2l = (const bf16x8*)(gw + 16384);

    const int t = threadIdx.x;
    const int wave = t >> 6, lane = t & 63;
    const int p0 = blockIdx.x * EPB;

    if (t < 64) { sB1[t] = b1[t]; sB2[t] = b2[t]; }
    if (t == 252) sDprev = (p0 > 0) ? dsts[p0 - 1] : -1;
    if (t == 253) sDnext = (p0 + EPB < EE) ? dsts[p0 + EPB] : -1;

    {   // gather h[src] -> split bf16 A1 rows; 2 threads/edge
        const int e = t >> 1, half = t & 1;
        const int p = p0 + e;
        const int src = srcs[p];
        const float4* hp = (const float4*)(h + (size_t)src * HID + half * 32);
        uint4* ah = (uint4*)(uA1h + e * AP1 + half * 32);
        uint4* al = (uint4*)(uA1l + e * AP1 + half * 32);
#pragma unroll
        for (int i = 0; i < 4; ++i) {
            const float4 v0 = hp[2 * i], v1 = hp[2 * i + 1];
            unsigned h0, l0, h1, l1, h2, l2, h3, l3;
            split2(v0.x, v0.y, h0, l0);
            split2(v0.z, v0.w, h1, l1);
            split2(v1.x, v1.y, h2, l2);
            split2(v1.z, v1.w, h3, l3);
            ah[i] = make_uint4(h0, h1, h2, h3);
            al[i] = make_uint4(l0, l1, l2, l3);
        }
        if (half) {   // edge_attr at k 64..67; ZERO k 68..95 (hi and lo)
            const float4 a = *(const float4*)(eas + (size_t)p * EDD);
            unsigned h0, l0, h1, l1;
            split2(a.x, a.y, h0, l0);
            split2(a.z, a.w, h1, l1);
            uint4* eh = (uint4*)(uA1h + e * AP1 + 64);
            uint4* el = (uint4*)(uA1l + e * AP1 + 64);
            const uint4 z = make_uint4(0u, 0u, 0u, 0u);
            eh[0] = make_uint4(h0, h1, 0u, 0u);
            eh[1] = z; eh[2] = z; eh[3] = z;
            el[0] = make_uint4(l0, l1, 0u, 0u);
            el[1] = z; el[2] = z; el[3] = z;
        } else {
            sDst[e] = dsts[p];
        }
    }
    __syncthreads();   // (1) A1 + tables ready

    // ---- stage 1: [128 x 96] @ [96 x 64], 3-term split products ----
    const int er0 = wave * 32;
    const int lrow = lane & 15, lgrp = lane >> 4;
    f32x4 acc1[2][4];
#pragma unroll
    for (int mt = 0; mt < 2; ++mt)
#pragma unroll
        for (int nt = 0; nt < 4; ++nt) {
            const float bv = sB1[nt * 16 + lrow];
            acc1[mt][nt] = (f32x4){bv, bv, bv, bv};
        }
#pragma unroll
    for (int ks = 0; ks < 3; ++ks) {
        bf16x8 aH[2], aL[2];
#pragma unroll
        for (int mt = 0; mt < 2; ++mt) {
            const int off = (er0 + mt * 16 + lrow) * AP1 + ks * 32 + lgrp * 8;
            aH[mt] = *(const bf16x8*)&uA1h[off];
            aL[mt] = *(const bf16x8*)&uA1l[off];
        }
#pragma unroll
        for (int nt = 0; nt < 4; ++nt) {
            const int fi = (ks * 4 + nt) * 64 + lane;
            const bf16x8 bH = gW1h[fi];
            const bf16x8 bL = gW1l[fi];
#pragma unroll
            for (int mt = 0; mt < 2; ++mt) {
                acc1[mt][nt] = __builtin_amdgcn_mfma_f32_16x16x32_bf16(aH[mt], bH, acc1[mt][nt], 0, 0, 0);
                acc1[mt][nt] = __builtin_amdgcn_mfma_f32_16x16x32_bf16(aH[mt], bL, acc1[mt][nt], 0, 0, 0);
                acc1[mt][nt] = __builtin_amdgcn_mfma_f32_16x16x32_bf16(aL[mt], bH, acc1[mt][nt], 0, 0, 0);
            }
        }
    }
    __syncthreads();   // (2) all A1 reads done; union rewritable

    // ---- relu + split, D-frag -> A2[edge][k2] ----
#pragma unroll
    for (int mt = 0; mt < 2; ++mt)
#pragma unroll
        for (int nt = 0; nt < 4; ++nt)
#pragma unroll
            for (int r = 0; r < 4; ++r) {
                const int edge = er0 + mt * 16 + lgrp * 4 + r;
                const float v = fmaxf(acc1[mt][nt][r], 0.f);
                const unsigned short hi = f2bf(v);
                uA2h[edge * 72 + nt * 16 + lrow] = hi;
                uA2l[edge * 72 + nt * 16 + lrow] = f2bf(v - bf2f(hi));
            }

    // ---- segmentation (wave 0): ballot scan over 128 start flags ----
    if (wave == 0) {
        const int e0 = lane, e1 = lane + 64;
        const int d0 = sDst[e0], d1 = sDst[e1];
        const int f0 = (e0 == 0) ? 1 : (d0 != sDst[e0 - 1] ? 1 : 0);
        const int f1 = (d1 != sDst[e1 - 1]) ? 1 : 0;
        const unsigned long long m0 = __ballot(f0);
        const unsigned long long m1 = __ballot(f1);
        const unsigned long long below = (1ull << lane) - 1ull;
        const int c0 = __popcll(m0);
        const int s0 = __popcll(m0 & below) + f0 - 1;
        const int s1 = c0 + __popcll(m1 & below) + f1 - 1;
        sSeg[e0] = s0; sSeg[e1] = s1;
        if (f0) sSegNode[s0] = d0;
        if (f1) sSegNode[s1] = d1;
        const int nseg = c0 + __popcll(m1);
        if (lane == 0) sNseg = nseg;
#pragma unroll
        for (int hh = 0; hh < 2; ++hh) {
            const int s = lane + hh * 64;
            if (s < nseg) {
                int fl = 1;
                if (s == 0) fl &= (sDst[0] != sDprev) ? 1 : 0;
                if (s == nseg - 1) fl &= (sDst[127] != sDnext) ? 1 : 0;
                sSegFlag[s] = fl;
            }
        }
    }
    __syncthreads();   // (3) A2 + seg tables visible to all

    // ---- stage 2: [128 x 64] @ [64 x 64], 3-term split products ----
    f32x4 acc2[2][4];
#pragma unroll
    for (int mt = 0; mt < 2; ++mt)
#pragma unroll
        for (int nt = 0; nt < 4; ++nt) {
            const float bv = sB2[nt * 16 + lrow];
            acc2[mt][nt] = (f32x4){bv, bv, bv, bv};
        }
#pragma unroll
    for (int ks = 0; ks < 2; ++ks) {
        bf16x8 aH[2], aL[2];
#pragma unroll
        for (int mt = 0; mt < 2; ++mt) {
            const int off = (er0 + mt * 16 + lrow) * 72 + ks * 32 + lgrp * 8;
            aH[mt] = *(const bf16x8*)&uA2h[off];
            aL[mt] = *(const bf16x8*)&uA2l[off];
        }
#pragma unroll
        for (int nt = 0; nt < 4; ++nt) {
            const int fi = (ks * 4 + nt) * 64 + lane;
            const bf16x8 bH = gW2h[fi];
            const bf16x8 bL = gW2l[fi];
#pragma unroll
            for (int mt = 0; mt < 2; ++mt) {
                acc2[mt][nt] = __builtin_amdgcn_mfma_f32_16x16x32_bf16(aH[mt], bH, acc2[mt][nt], 0, 0, 0);
                acc2[mt][nt] = __builtin_amdgcn_mfma_f32_16x16x32_bf16(aH[mt], bL, acc2[mt][nt], 0, 0, 0);
                acc2[mt][nt] = __builtin_amdgcn_mfma_f32_16x16x32_bf16(aL[mt], bH, acc2[mt][nt], 0, 0, 0);
            }
        }
    }
    __syncthreads();   // (4) A2 reads done; union becomes segbuf

    {   // zero segbuf
        const float4 z = make_float4(0.f, 0.f, 0.f, 0.f);
        float4* sb4 = (float4*)segbuf;
        for (int i = t; i < 2048; i += 256) sb4[i] = z;
    }
    __syncthreads();   // (5)

    // ---- LDS segmented accumulate (run-merged) ----
#pragma unroll
    for (int mt = 0; mt < 2; ++mt) {
        int sg[4];
#pragma unroll
        for (int r = 0; r < 4; ++r) sg[r] = sSeg[er0 + mt * 16 + lgrp * 4 + r];
#pragma unroll
        for (int nt = 0; nt < 4; ++nt) {
            const int col = nt * 16 + lrow;
            float rv = acc2[mt][nt][0];
            int cs = sg[0];
#pragma unroll
            for (int r = 1; r < 4; ++r) {
                if (sg[r] == cs) rv += acc2[mt][nt][r];
                else { atomicAdd(&segbuf[cs * 64 + col], rv); cs = sg[r]; rv = acc2[mt][nt][r]; }
            }
            atomicAdd(&segbuf[cs * 64 + col], rv);
        }
    }
    __syncthreads();   // (6)

    // ---- write out: interior segs plain store, boundary segs atomic ----
    const int nseg = sNseg;
    for (int s = wave; s < nseg; s += 4) {
        const float v = segbuf[s * 64 + lane];
        float* ap = agg + (size_t)sSegNode[s] * HID + lane;
        if (sSegFlag[s]) *ap = v;
        else atomicAdd(ap, v);
    }
}

// ---- fallback path (atomic scatter), used only if ws_size is too small ----
__global__ __launch_bounds__(256) void k_edge(const float* __restrict__ h,
    const int* __restrict__ ei32, const float* __restrict__ ea,
    const float* __restrict__ W1, const float* __restrict__ b1,
    const float* __restrict__ W2, const float* __restrict__ b2,
    float* __restrict__ agg)
{
    __shared__ float sAT[68 * PITCH];
    __shared__ float sW1[68 * HID];
    __shared__ float sW2[HID * HID];
    __shared__ float sB1[HID];
    __shared__ float sB2[HID];
    __shared__ int   sDst[EPB];
    const int t = threadIdx.x;
    const size_t e0 = (size_t)blockIdx.x * EPB;
    const int sh = ei_shift(ei32);

    for (int i = t; i < 68 * HID; i += 256) sW1[i] = W1[i];
    for (int i = t; i < HID * HID; i += 256) sW2[i] = W2[i];
    if (t < HID) { sB1[t] = b1[t]; sB2[t] = b2[t]; }
    if (t < EPB) sDst[t] = ei32[(EE + e0 + t) << sh];

    {
        const int e = t >> 1, half = t & 1;
        const int src = ei32[(e0 + e) << sh];
        const float* hp = h + (size_t)src * HID + half * 32;
#pragma unroll
        for (int k = 0; k < 32; k += 4) {
            const float4 v = *(const float4*)(hp + k);
            sAT[(half * 32 + k + 0) * PITCH + e] = v.x;
            sAT[(half * 32 + k + 1) * PITCH + e] = v.y;
            sAT[(half * 32 + k + 2) * PITCH + e] = v.z;
            sAT[(half * 32 + k + 3) * PITCH + e] = v.w;
        }
        if (half) {
            const float4 a = *(const float4*)(ea + (e0 + e) * EDD);
            sAT[(64 + 0) * PITCH + e] = a.x;
            sAT[(64 + 1) * PITCH + e] = a.y;
            sAT[(64 + 2) * PITCH + e] = a.z;
            sAT[(64 + 3) * PITCH + e] = a.w;
        }
    }
    __syncthreads();

    const int og = t & 15, eg = t >> 4;
    const int j0 = og * 4, le0 = eg * 8;
    float acc[8][4];
#pragma unroll
    for (int i = 0; i < 8; ++i)
#pragma unroll
        for (int j = 0; j < 4; ++j) acc[i][j] = sB1[j0 + j];
    for (int k = 0; k < 68; ++k) {
        const float4 b  = *(const float4*)&sW1[k * HID + j0];
        const float4 a0 = *(const float4*)&sAT[k * PITCH + le0];
        const float4 a1 = *(const float4*)&sAT[k * PITCH + le0 + 4];
        const float av[8] = {a0.x, a0.y, a0.z, a0.w, a1.x, a1.y, a1.z, a1.w};
        const float bv[4] = {b.x, b.y, b.z, b.w};
#pragma unroll
        for (int i = 0; i < 8; ++i)
#pragma unroll
            for (int j = 0; j < 4; ++j) acc[i][j] = fmaf(av[i], bv[j], acc[i][j]);
    }
    __syncthreads();
#pragma unroll
    for (int j = 0; j < 4; ++j) {
        const float4 w0 = make_float4(frelu(acc[0][j]), frelu(acc[1][j]),
                                      frelu(acc[2][j]), frelu(acc[3][j]));
        const float4 w1 = make_float4(frelu(acc[4][j]), frelu(acc[5][j]),
                                      frelu(acc[6][j]), frelu(acc[7][j]));
        *(float4*)&sAT[(j0 + j) * PITCH + le0] = w0;
        *(float4*)&sAT[(j0 + j) * PITCH + le0 + 4] = w1;
    }
    __syncthreads();
#pragma unroll
    for (int i = 0; i < 8; ++i)
#pragma unroll
        for (int j = 0; j < 4; ++j) acc[i][j] = sB2[j0 + j];
    for (int k = 0; k < HID; ++k) {
        const float4 b  = *(const float4*)&sW2[k * HID + j0];
        const float4 a0 = *(const float4*)&sAT[k * PITCH + le0];
        const float4 a1 = *(const float4*)&sAT[k * PITCH + le0 + 4];
        const float av[8] = {a0.x, a0.y, a0.z, a0.w, a1.x, a1.y, a1.z, a1.w};
        const float bv[4] = {b.x, b.y, b.z, b.w};
#pragma unroll
        for (int i = 0; i < 8; ++i)
#pragma unroll
            for (int j = 0; j < 4; ++j) acc[i][j] = fmaf(av[i], bv[j], acc[i][j]);
    }
#pragma unroll
    for (int i = 0; i < 8; ++i) {
        const int dst = sDst[le0 + i];
        float* ap = agg + (size_t)dst * HID + j0;
#pragma unroll
        for (int j = 0; j < 4; ++j) atomicAdd(ap + j, acc[i][j]);
    }
}

// -------------------- BN stats --------------------
__global__ __launch_bounds__(256) void k_bnstats(const float* __restrict__ agg,
    float* __restrict__ stats)
{
    const int c = threadIdx.x & 63;
    const int rg = threadIdx.x >> 6;
    float s = 0.f, ss = 0.f;
    for (size_t n = (size_t)blockIdx.x * 4 + rg; n < NN; n += (size_t)gridDim.x * 4) {
        const float v = agg[n * HID + c];
        s += v;
        ss = fmaf(v, v, ss);
    }
    __shared__ float rs[4][64];
    __shared__ float rss[4][64];
    rs[rg][c] = s; rss[rg][c] = ss;
    __syncthreads();
    if (rg == 0) {
        s  = rs[0][c] + rs[1][c] + rs[2][c] + rs[3][c];
        ss = rss[0][c] + rss[1][c] + rss[2][c] + rss[3][c];
        atomicAdd(&stats[c], s);
        atomicAdd(&stats[64 + c], ss);
    }
}

// -------------------- h += relu(BN(agg)) --------------------
__global__ __launch_bounds__(256) void k_update(const float* __restrict__ agg,
    const float* __restrict__ stats, const float* __restrict__ gamma,
    const float* __restrict__ beta, float* __restrict__ h)
{
    const size_t i = (size_t)blockIdx.x * 256 + threadIdx.x;
    const int c = (int)(i & 63);
    const float mu  = stats[c] * (1.f / NN);
    const float var = fmaf(-mu, mu, stats[64 + c] * (1.f / NN));
    const float inv = rsqrtf(var + BNEPS);
    const float v = fmaf((agg[i] - mu) * inv, gamma[c], beta[c]);
    h[i] += frelu(v);
}

// -------------------- out = relu(h @ W3 + b3) @ W4 + b4 --------------------
__global__ __launch_bounds__(256) void k_out(const float* __restrict__ h,
    const float* __restrict__ W3, const float* __restrict__ b3,
    const float* __restrict__ W4, const float* __restrict__ b4,
    float* __restrict__ out)
{
    __shared__ float sAT[64 * PITCH];
    __shared__ float sW3[HID * HID];
    __shared__ float sW4[HID * 4];
    __shared__ float sB3[HID];
    __shared__ float sB4[4];
    const int t = threadIdx.x;
    const size_t n0 = (size_t)blockIdx.x * 128;

    for (int i = t; i < HID * HID; i += 256) sW3[i] = W3[i];
    if (t < HID * ODD) sW4[(t / ODD) * 4 + (t % ODD)] = W4[t];
    if (t < HID) sB3[t] = b3[t];
    if (t < ODD) sB4[t] = b4[t];

    {
        const int e = t >> 1, half = t & 1;
        const size_t n = n0 + e;
        if (n < NN) {
            const float* hp = h + n * HID + half * 32;
#pragma unroll
            for (int k = 0; k < 32; k += 4) {
                const float4 v = *(const float4*)(hp + k);
                sAT[(half * 32 + k + 0) * PITCH + e] = v.x;
                sAT[(half * 32 + k + 1) * PITCH + e] = v.y;
                sAT[(half * 32 + k + 2) * PITCH + e] = v.z;
                sAT[(half * 32 + k + 3) * PITCH + e] = v.w;
            }
        } else {
#pragma unroll
            for (int k = 0; k < 32; ++k) sAT[(half * 32 + k) * PITCH + e] = 0.f;
        }
    }
    __syncthreads();

    const int og = t & 15, eg = t >> 4;
    const int j0 = og * 4, le0 = eg * 8;
    float acc[8][4];
#pragma unroll
    for (int i = 0; i < 8; ++i)
#pragma unroll
        for (int j = 0; j < 4; ++j) acc[i][j] = sB3[j0 + j];

    for (int k = 0; k < HID; ++k) {
        const float4 b  = *(const float4*)&sW3[k * HID + j0];
        const float4 a0 = *(const float4*)&sAT[k * PITCH + le0];
        const float4 a1 = *(const float4*)&sAT[k * PITCH + le0 + 4];
        const float av[8] = {a0.x, a0.y, a0.z, a0.w, a1.x, a1.y, a1.z, a1.w};
        const float bv[4] = {b.x, b.y, b.z, b.w};
#pragma unroll
        for (int i = 0; i < 8; ++i)
#pragma unroll
            for (int j = 0; j < 4; ++j) acc[i][j] = fmaf(av[i], bv[j], acc[i][j]);
    }
    __syncthreads();

#pragma unroll
    for (int j = 0; j < 4; ++j) {
        const float4 w0 = make_float4(frelu(acc[0][j]), frelu(acc[1][j]),
                                      frelu(acc[2][j]), frelu(acc[3][j]));
        const float4 w1 = make_float4(frelu(acc[4][j]), frelu(acc[5][j]),
                                      frelu(acc[6][j]), frelu(acc[7][j]));
        *(float4*)&sAT[(j0 + j) * PITCH + le0] = w0;
        *(float4*)&sAT[(j0 + j) * PITCH + le0 + 4] = w1;
    }
    __syncthreads();

    if (t < 128) {
        const size_t n = n0 + t;
        if (n < NN) {
            float o[3] = {sB4[0], sB4[1], sB4[2]};
            for (int k = 0; k < HID; ++k) {
                const float v = sAT[k * PITCH + t];
                o[0] = fmaf(v, sW4[k * 4 + 0], o[0]);
                o[1] = fmaf(v, sW4[k * 4 + 1], o[1]);
                o[2] = fmaf(v, sW4[k * 4 + 2], o[2]);
            }
            out[n * 3 + 0] = o[0];
            out[n * 3 + 1] = o[1];
            out[n * 3 + 2] = o[2];
        }
    }
}

extern "C" void kernel_launch(void* const* d_in, const int* in_sizes, int n_in,
                              void* d_out, int out_size, void* d_ws, size_t ws_size,
                              hipStream_t stream)
{
    const float* x   = (const float*)d_in[0];
    const int*   ei  = (const int*)d_in[1];
    const float* ea  = (const float*)d_in[2];
    const float* Win = (const float*)d_in[3];
    const float* bin = (const float*)d_in[4];
    const float* W1  = (const float*)d_in[5];
    const float* b1  = (const float*)d_in[6];
    const float* W2  = (const float*)d_in[7];
    const float* b2  = (const float*)d_in[8];
    const float* gam = (const float*)d_in[9];
    const float* bet = (const float*)d_in[10];
    const float* W3  = (const float*)d_in[11];
    const float* b3  = (const float*)d_in[12];
    const float* W4  = (const float*)d_in[13];
    const float* b4  = (const float*)d_in[14];
    float* out = (float*)d_out;

    // workspace layout (~97 MB)
    float* h     = (float*)d_ws;                     // NN*HID
    float* agg   = h + (size_t)NN * HID;             // NN*HID
    float* stats = agg + (size_t)NN * HID;           // 128
    int* deg      = (int*)(stats + 128);             // NN
    int* rowstart = deg + NN;                        // NN+1
    int* cursor   = rowstart + NN + 1;               // NN
    int* bsum     = cursor + NN;                     // 512
    int* bpre     = bsum + 512;                      // 512
    int* eperm    = bpre + 512;                      // EE
    int* dsts     = eperm + EE;                      // EE
    int* srcs     = dsts + EE;                       // EE
    size_t off = (size_t)((char*)(srcs + EE) - (char*)d_ws);
    off = (off + 15) & ~(size_t)15;
    unsigned short* gw = (unsigned short*)((char*)d_ws + off);   // 3*WFRAG shorts
    off += (size_t)NL * WFRAG * sizeof(unsigned short);
    off = (off + 15) & ~(size_t)15;
    float* eas = (float*)((char*)d_ws + off);                    // EE*EDD floats
    const size_t need = off + (size_t)EE * EDD * sizeof(float);
    const bool sorted_path = (ws_size >= need);

    k_input<<<NN / 32, 256, 0, stream>>>(x, Win, bin, h);

    if (sorted_path) {
        hipMemsetAsync(deg, 0, (size_t)NN * sizeof(int), stream);
        k_hist<<<(EE + 255) / 256, 256, 0, stream>>>(ei, deg);
        k_part<<<NB, 256, 0, stream>>>(deg, bsum);
        k_top<<<1, 64, 0, stream>>>(bsum, bpre);
        k_scan_add<<<NB, 256, 0, stream>>>(deg, bpre, rowstart, cursor);
        k_permute<<<(EE + 255) / 256, 256, 0, stream>>>(ei, cursor, eperm);
        k_gs<<<(EE + 255) / 256, 256, 0, stream>>>(ei, eperm, ea, srcs, dsts, eas);
        k_wprep<<<NL, 256, 0, stream>>>(W1, W2, gw);

        for (int l = 0; l < NL; ++l) {
            hipMemsetAsync(agg, 0, ((size_t)NN * HID + 128) * sizeof(float), stream);
            k_mlpf<<<EE / EPB, 256, 0, stream>>>(h, srcs, dsts, eas,
                gw + (size_t)l * WFRAG, b1 + (size_t)l * HID, b2 + (size_t)l * HID, agg);
            k_bnstats<<<512, 256, 0, stream>>>(agg, stats);
            k_update<<<(NN * HID) / 256, 256, 0, stream>>>(agg, stats,
                gam + (size_t)l * HID, bet + (size_t)l * HID, h);
        }
    } else {
        for (int l = 0; l < NL; ++l) {
            hipMemsetAsync(agg, 0, ((size_t)NN * HID + 128) * sizeof(float), stream);
            k_edge<<<EE / EPB, 256, 0, stream>>>(h, ei, ea,
                W1 + (size_t)l * (HID + EDD) * HID, b1 + (size_t)l * HID,
                W2 + (size_t)l * HID * HID, b2 + (size_t)l * HID, agg);
            k_bnstats<<<512, 256, 0, stream>>>(agg, stats);
            k_update<<<(NN * HID) / 256, 256, 0, stream>>>(agg, stats,
                gam + (size_t)l * HID, bet + (size_t)l * HID, h);
        }
    }

    k_out<<<(NN + 127) / 128, 256, 0, stream>>>(h, W3, b3, W4, b4, out);
}